// Round 2
// baseline (1276.774 us; speedup 1.0000x reference)
//
#include <hip/hip_runtime.h>

#define HD 128
#define EMB 64
#define EPS 1e-5f

__device__ __forceinline__ float4 ld4(const float* p) {
    return *reinterpret_cast<const float4*>(p);
}

// ---------------- degree histogram ----------------
__global__ void k_hist(const int* __restrict__ dst, int* __restrict__ deg, int e) {
    int i = blockIdx.x * blockDim.x + threadIdx.x;
    if (i < e) atomicAdd(&deg[dst[i]], 1);
}

__global__ void k_dinv(const int* __restrict__ deg, float* __restrict__ dinv, int n) {
    int i = blockIdx.x * blockDim.x + threadIdx.x;
    if (i < n) dinv[i] = 1.0f / sqrtf((float)deg[i] + 1.0f);
}

// ---------------- exclusive scan (3-phase) ----------------
__global__ void k_scan_part(const int* __restrict__ deg, int* __restrict__ out,
                            int* __restrict__ bsum, int n) {
    __shared__ int s[256];
    int i = blockIdx.x * 256 + threadIdx.x;
    int v = (i < n) ? deg[i] : 0;
    s[threadIdx.x] = v;
    __syncthreads();
    #pragma unroll
    for (int off = 1; off < 256; off <<= 1) {
        int t = (threadIdx.x >= off) ? s[threadIdx.x - off] : 0;
        __syncthreads();
        s[threadIdx.x] += t;
        __syncthreads();
    }
    if (i < n) out[i] = s[threadIdx.x] - v;         // exclusive
    if (threadIdx.x == 255) bsum[blockIdx.x] = s[255];
}

__global__ void k_scan_mid(int* __restrict__ bsum, int nb) {
    __shared__ int s[512];
    int t = threadIdx.x;
    int v = (t < nb) ? bsum[t] : 0;
    s[t] = v;
    __syncthreads();
    for (int off = 1; off < 512; off <<= 1) {
        int u = (t >= off) ? s[t - off] : 0;
        __syncthreads();
        s[t] += u;
        __syncthreads();
    }
    if (t < nb) bsum[t] = s[t] - v;                 // exclusive block offsets
}

__global__ void k_scan_add(int* __restrict__ rs, const int* __restrict__ bsum,
                           int n, int e_total) {
    int i = blockIdx.x * 256 + threadIdx.x;
    if (i < n) rs[i] += bsum[blockIdx.x];
    if (i == 0) rs[n] = e_total;
}

// ---------------- CSR scatter ----------------
__global__ void k_scatter(const int* __restrict__ src, const int* __restrict__ dst,
                          int* __restrict__ cursor, int* __restrict__ csr_src, int e) {
    int i = blockIdx.x * blockDim.x + threadIdx.x;
    if (i < e) {
        int d = dst[i];
        int pos = atomicAdd(&cursor[d], 1);
        csr_src[pos] = src[i];
    }
}

// ---------------- fp32 tiled GEMM: C[M,128] = act(A[M,128]) @ W[128,128] ----------------
// APPLY_BN: A element -> relu(a*x+b) during staging (per-K-column affine)
// OUT_BIAS_RELU: C -> relu(C + bias[col])
template <bool APPLY_BN, bool OUT_BIAS_RELU>
__global__ void k_gemm(const float* __restrict__ A, const float* __restrict__ W,
                       const float* __restrict__ bias,
                       const float* __restrict__ aff_a, const float* __restrict__ aff_b,
                       float* __restrict__ C, int M) {
    __shared__ float As[32][64];    // [k][m]
    __shared__ float Bs[32][128];   // [k][n]
    const int tid = threadIdx.x;
    const int tx = tid & 31;   // col group (4 cols)
    const int ty = tid >> 5;   // row group (8 rows)
    const int row0 = blockIdx.x * 64;

    float acc[8][4];
    #pragma unroll
    for (int i = 0; i < 8; ++i)
        #pragma unroll
        for (int j = 0; j < 4; ++j) acc[i][j] = 0.0f;

    for (int k0 = 0; k0 < HD; k0 += 32) {
        // stage A tile (64 rows x 32 k), transposed into [k][m]
        #pragma unroll
        for (int it = 0; it < 2; ++it) {
            int idx = tid + it * 256;          // 0..511
            int m = idx >> 3;
            int k4 = (idx & 7) << 2;
            int gm = row0 + m;
            float4 v = make_float4(0.f, 0.f, 0.f, 0.f);
            if (gm < M) v = ld4(A + (size_t)gm * HD + k0 + k4);
            if (APPLY_BN) {
                float4 a4 = ld4(aff_a + k0 + k4);
                float4 b4 = ld4(aff_b + k0 + k4);
                v.x = fmaxf(fmaf(v.x, a4.x, b4.x), 0.f);
                v.y = fmaxf(fmaf(v.y, a4.y, b4.y), 0.f);
                v.z = fmaxf(fmaf(v.z, a4.z, b4.z), 0.f);
                v.w = fmaxf(fmaf(v.w, a4.w, b4.w), 0.f);
            }
            As[k4 + 0][m] = v.x; As[k4 + 1][m] = v.y;
            As[k4 + 2][m] = v.z; As[k4 + 3][m] = v.w;
        }
        // stage B tile (32 k x 128 n)
        #pragma unroll
        for (int it = 0; it < 4; ++it) {
            int idx = tid + it * 256;          // 0..1023
            int kk = idx >> 5;
            int n4 = (idx & 31) << 2;
            *reinterpret_cast<float4*>(&Bs[kk][n4]) = ld4(W + (size_t)(k0 + kk) * HD + n4);
        }
        __syncthreads();
        #pragma unroll
        for (int k = 0; k < 32; ++k) {
            float4 b4 = *reinterpret_cast<const float4*>(&Bs[k][tx * 4]);
            float4 a0 = *reinterpret_cast<const float4*>(&As[k][ty * 8]);
            float4 a1 = *reinterpret_cast<const float4*>(&As[k][ty * 8 + 4]);
            float a[8] = {a0.x, a0.y, a0.z, a0.w, a1.x, a1.y, a1.z, a1.w};
            float b[4] = {b4.x, b4.y, b4.z, b4.w};
            #pragma unroll
            for (int i = 0; i < 8; ++i)
                #pragma unroll
                for (int j = 0; j < 4; ++j)
                    acc[i][j] = fmaf(a[i], b[j], acc[i][j]);
        }
        __syncthreads();
    }
    #pragma unroll
    for (int i = 0; i < 8; ++i) {
        int gm = row0 + ty * 8 + i;
        if (gm < M) {
            float4 o = make_float4(acc[i][0], acc[i][1], acc[i][2], acc[i][3]);
            if (OUT_BIAS_RELU) {
                float4 bb = ld4(bias + tx * 4);
                o.x = fmaxf(o.x + bb.x, 0.f);
                o.y = fmaxf(o.y + bb.y, 0.f);
                o.z = fmaxf(o.z + bb.z, 0.f);
                o.w = fmaxf(o.w + bb.w, 0.f);
            }
            *reinterpret_cast<float4*>(C + (size_t)gm * HD + tx * 4) = o;
        }
    }
}

// ---------------- per-node aggregation + BN stats (wave-per-node, float2) ----------------
// h_pre[n] = sum_{s in in(n)} hw[s]*dinv[s]*dinv[n] + hw[n]/deg[n] + bias
// Block: 256 threads = 4 waves; each wave owns one node (64 lanes x float2 = 512B row).
// Each wave processes NPB nodes sequentially; block covers 4*NPB consecutive nodes.
#define NPB 16
__global__ void k_agg(const float* __restrict__ hw, const int* __restrict__ row_start,
                      const int* __restrict__ csr_src, const float* __restrict__ dinv,
                      const float* __restrict__ bias_row, float* __restrict__ h_pre,
                      float* __restrict__ colsum, float* __restrict__ colsumsq, int n) {
    const int tid = threadIdx.x;
    const int lane = tid & 63;     // feature pair index
    const int slot = tid >> 6;     // wave id 0..3
    const int n0 = blockIdx.x * (4 * NPB);
    const float2* __restrict__ hw2 = (const float2*)hw;
    float2* __restrict__ hp2 = (float2*)h_pre;
    const float2 bias2 = *((const float2*)bias_row + lane);

    float2 psum = make_float2(0.f, 0.f);
    float2 psq  = make_float2(0.f, 0.f);

    for (int nn = 0; nn < NPB; ++nn) {
        int node = n0 + nn * 4 + slot;
        if (node < n) {
            float dn = dinv[node];
            float2 own = hw2[(size_t)node * 64 + lane];
            float sn = dn * dn;
            float2 acc = make_float2(fmaf(own.x, sn, bias2.x),
                                     fmaf(own.y, sn, bias2.y));
            int jb = row_start[node], je = row_start[node + 1];
            for (int j = jb; j < je; ++j) {
                int s = csr_src[j];                 // wave-uniform
                float w = dinv[s] * dn;             // wave-uniform
                float2 v = hw2[(size_t)s * 64 + lane];
                acc.x = fmaf(v.x, w, acc.x);
                acc.y = fmaf(v.y, w, acc.y);
            }
            hp2[(size_t)node * 64 + lane] = acc;
            psum.x += acc.x; psum.y += acc.y;
            psq.x = fmaf(acc.x, acc.x, psq.x);
            psq.y = fmaf(acc.y, acc.y, psq.y);
        }
    }

    // reduce the 4 slots in LDS, then 128 atomics per block
    __shared__ float2 redA[256];
    __shared__ float2 redB[256];
    redA[tid] = psum;
    redB[tid] = psq;
    __syncthreads();
    if (slot == 0) {
        #pragma unroll
        for (int s = 1; s < 4; ++s) {
            float2 a = redA[lane + s * 64], b = redB[lane + s * 64];
            psum.x += a.x; psum.y += a.y;
            psq.x += b.x;  psq.y += b.y;
        }
        atomicAdd(&colsum[lane * 2 + 0], psum.x);
        atomicAdd(&colsum[lane * 2 + 1], psum.y);
        atomicAdd(&colsumsq[lane * 2 + 0], psq.x);
        atomicAdd(&colsumsq[lane * 2 + 1], psq.y);
    }
}

// ---------------- BN coefficients (+ reset accumulators for next layer) ----------------
__global__ void k_bncoef(float* __restrict__ colsum, float* __restrict__ colsumsq,
                         const float* __restrict__ gamma, const float* __restrict__ beta,
                         float* __restrict__ aff_a, float* __restrict__ aff_b, int n) {
    int f = threadIdx.x;
    float inv_n = 1.0f / (float)n;
    float mean = colsum[f] * inv_n;
    float var = colsumsq[f] * inv_n - mean * mean;
    float rstd = 1.0f / sqrtf(var + EPS);
    float a = gamma[f] * rstd;
    aff_a[f] = a;
    aff_b[f] = beta[f] - mean * a;
    colsum[f] = 0.f;
    colsumsq[f] = 0.f;
}

// ---------------- graph boundaries (batch sorted) ----------------
__global__ void k_gbounds(const int* __restrict__ batch, int* __restrict__ gstart,
                          int n, int g) {
    int gi = blockIdx.x * blockDim.x + threadIdx.x;
    if (gi > g) return;
    int lo = 0, hi = n;
    while (lo < hi) {
        int mid = (lo + hi) >> 1;
        if (batch[mid] < gi) lo = mid + 1; else hi = mid;
    }
    gstart[gi] = lo;
}

// ---------------- per-graph mean pool with fused BN+relu (float2, 2 half-waves) --------
__global__ void k_pool(const float* __restrict__ h_pre, const int* __restrict__ gstart,
                       const float* __restrict__ aff_a, const float* __restrict__ aff_b,
                       float* __restrict__ pooled) {
    const int gi = blockIdx.x;
    const int tid = threadIdx.x;
    const int lane = tid & 63;
    const int half = tid >> 6;          // 0/1: alternate rows
    const float2* __restrict__ h2 = (const float2*)h_pre;
    const float2 a2 = *((const float2*)aff_a + lane);
    const float2 b2 = *((const float2*)aff_b + lane);
    int s = gstart[gi], e = gstart[gi + 1];
    float2 sum = make_float2(0.f, 0.f);
    for (int i = s + half; i < e; i += 2) {
        float2 v = h2[(size_t)i * 64 + lane];
        sum.x += fmaxf(fmaf(v.x, a2.x, b2.x), 0.f);
        sum.y += fmaxf(fmaf(v.y, a2.y, b2.y), 0.f);
    }
    __shared__ float2 red[128];
    red[tid] = sum;
    __syncthreads();
    if (half == 0) {
        float2 o = red[tid + 64];
        sum.x += o.x; sum.y += o.y;
        float inv = 1.0f / fmaxf((float)(e - s), 1.0f);
        float2* p2 = (float2*)pooled;
        p2[(size_t)gi * 64 + lane] = make_float2(sum.x * inv, sum.y * inv);
    }
}

// ---------------- head MLP: out = relu(p@W1+b1)@W2+b2 ----------------
__global__ void k_head(const float* __restrict__ pooled, const float* __restrict__ W1,
                       const float* __restrict__ b1, const float* __restrict__ W2,
                       const float* __restrict__ b2, float* __restrict__ out) {
    __shared__ float p[HD];
    __shared__ float t[HD];
    int gi = blockIdx.x;
    int j = threadIdx.x;
    p[j] = pooled[(size_t)gi * HD + j];
    __syncthreads();
    float acc = b1[j];
    #pragma unroll 8
    for (int k = 0; k < HD; ++k) acc = fmaf(p[k], W1[(size_t)k * HD + j], acc);
    t[j] = fmaxf(acc, 0.f);
    __syncthreads();
    if (j < EMB) {
        float o = b2[j];
        #pragma unroll 8
        for (int k = 0; k < HD; ++k) o = fmaf(t[k], W2[(size_t)k * EMB + j], o);
        out[(size_t)gi * EMB + j] = o;
    }
}

extern "C" void kernel_launch(void* const* d_in, const int* in_sizes, int n_in,
                              void* d_out, int out_size, void* d_ws, size_t ws_size,
                              hipStream_t stream) {
    const float* x     = (const float*)d_in[0];
    const int*   ei    = (const int*)d_in[1];
    const int*   batch = (const int*)d_in[2];
    const float* W_in  = (const float*)d_in[3];
    const float* b_in  = (const float*)d_in[4];
    const float* Ws    = (const float*)d_in[5];
    const float* bs    = (const float*)d_in[6];
    const float* gam   = (const float*)d_in[7];
    const float* bet   = (const float*)d_in[8];
    const float* W1    = (const float*)d_in[9];
    const float* b1    = (const float*)d_in[10];
    const float* W2    = (const float*)d_in[11];
    const float* b2    = (const float*)d_in[12];
    float* out = (float*)d_out;

    const int n = in_sizes[0] / HD;   // 100000
    const int e = in_sizes[1] / 2;    // 1600000
    const int g = out_size / EMB;     // 1024

    const int* esrc = ei;
    const int* edst = ei + e;

    // ---- workspace carve (256B aligned) ----
    char* w = (char*)d_ws;
    auto alloc = [&](size_t bytes) {
        char* p = w;
        w += (bytes + 255) & ~(size_t)255;
        return p;
    };
    float* hbuf    = (float*)alloc((size_t)n * HD * 4);
    float* hw      = (float*)alloc((size_t)n * HD * 4);
    int*   csr_src = (int*)alloc((size_t)e * 4);
    int*   deg     = (int*)alloc((size_t)n * 4);
    float* dinv    = (float*)alloc((size_t)n * 4);
    int*   rstart  = (int*)alloc((size_t)(n + 1) * 4);
    int*   cursor  = (int*)alloc((size_t)n * 4);
    int*   bsum    = (int*)alloc(512 * 4);
    float* colsum  = (float*)alloc(256 * 4);
    float* colsumsq = colsum + HD;
    float* aff_a   = (float*)alloc(256 * 4);
    float* aff_b   = aff_a + HD;
    int*   gstart  = (int*)alloc((size_t)(g + 1) * 4);
    float* pooled  = (float*)alloc((size_t)g * HD * 4);

    hipMemsetAsync(deg, 0, (size_t)n * 4, stream);
    hipMemsetAsync(colsum, 0, 256 * 4, stream);

    const int eb = (e + 255) / 256;
    const int nb = (n + 255) / 256;

    k_hist<<<eb, 256, 0, stream>>>(edst, deg, e);
    k_dinv<<<nb, 256, 0, stream>>>(deg, dinv, n);
    k_scan_part<<<nb, 256, 0, stream>>>(deg, rstart, bsum, n);
    k_scan_mid<<<1, 512, 0, stream>>>(bsum, nb);
    k_scan_add<<<nb, 256, 0, stream>>>(rstart, bsum, n, e);
    hipMemcpyAsync(cursor, rstart, (size_t)n * 4, hipMemcpyDeviceToDevice, stream);
    k_scatter<<<eb, 256, 0, stream>>>(esrc, edst, cursor, csr_src, e);

    const int gb = (n + 63) / 64;
    // input projection: h = relu(x @ W_in + b_in)
    k_gemm<false, true><<<gb, 256, 0, stream>>>(x, W_in, b_in, nullptr, nullptr, hbuf, n);

    const int ab = (n + 4 * NPB - 1) / (4 * NPB);
    for (int i = 0; i < 3; ++i) {
        if (i == 0)
            k_gemm<false, false><<<gb, 256, 0, stream>>>(
                hbuf, Ws + (size_t)i * HD * HD, nullptr, nullptr, nullptr, hw, n);
        else
            k_gemm<true, false><<<gb, 256, 0, stream>>>(
                hbuf, Ws + (size_t)i * HD * HD, nullptr, aff_a, aff_b, hw, n);
        k_agg<<<ab, 256, 0, stream>>>(hw, rstart, csr_src, dinv, bs + (size_t)i * HD,
                                      hbuf, colsum, colsumsq, n);
        k_bncoef<<<1, HD, 0, stream>>>(colsum, colsumsq, gam + (size_t)i * HD,
                                       bet + (size_t)i * HD, aff_a, aff_b, n);
    }

    k_gbounds<<<(g + 256) / 256, 256, 0, stream>>>(batch, gstart, n, g);
    k_pool<<<g, 128, 0, stream>>>(hbuf, gstart, aff_a, aff_b, pooled);
    k_head<<<g, HD, 0, stream>>>(pooled, W1, b1, W2, b2, out);
}

// Round 3
// 1263.978 us; speedup vs baseline: 1.0101x; 1.0101x over previous
//
#include <hip/hip_runtime.h>

#define HD 128
#define EMB 64
#define EPS 1e-5f

__device__ __forceinline__ float4 ld4(const float* p) {
    return *reinterpret_cast<const float4*>(p);
}

// ---------------- degree histogram ----------------
__global__ void k_hist(const int* __restrict__ dst, int* __restrict__ deg, int e) {
    int i = blockIdx.x * blockDim.x + threadIdx.x;
    if (i < e) atomicAdd(&deg[dst[i]], 1);
}

__global__ void k_dinv(const int* __restrict__ deg, float* __restrict__ dinv, int n) {
    int i = blockIdx.x * blockDim.x + threadIdx.x;
    if (i < n) dinv[i] = 1.0f / sqrtf((float)deg[i] + 1.0f);
}

// ---------------- exclusive scan (3-phase) ----------------
__global__ void k_scan_part(const int* __restrict__ deg, int* __restrict__ out,
                            int* __restrict__ bsum, int n) {
    __shared__ int s[256];
    int i = blockIdx.x * 256 + threadIdx.x;
    int v = (i < n) ? deg[i] : 0;
    s[threadIdx.x] = v;
    __syncthreads();
    #pragma unroll
    for (int off = 1; off < 256; off <<= 1) {
        int t = (threadIdx.x >= off) ? s[threadIdx.x - off] : 0;
        __syncthreads();
        s[threadIdx.x] += t;
        __syncthreads();
    }
    if (i < n) out[i] = s[threadIdx.x] - v;         // exclusive
    if (threadIdx.x == 255) bsum[blockIdx.x] = s[255];
}

__global__ void k_scan_mid(int* __restrict__ bsum, int nb) {
    __shared__ int s[512];
    int t = threadIdx.x;
    int v = (t < nb) ? bsum[t] : 0;
    s[t] = v;
    __syncthreads();
    for (int off = 1; off < 512; off <<= 1) {
        int u = (t >= off) ? s[t - off] : 0;
        __syncthreads();
        s[t] += u;
        __syncthreads();
    }
    if (t < nb) bsum[t] = s[t] - v;                 // exclusive block offsets
}

__global__ void k_scan_add(int* __restrict__ rs, const int* __restrict__ bsum,
                           int n, int e_total) {
    int i = blockIdx.x * 256 + threadIdx.x;
    if (i < n) rs[i] += bsum[blockIdx.x];
    if (i == 0) rs[n] = e_total;
}

// ---------------- CSR scatter ----------------
__global__ void k_scatter(const int* __restrict__ src, const int* __restrict__ dst,
                          int* __restrict__ cursor, int* __restrict__ csr_src, int e) {
    int i = blockIdx.x * blockDim.x + threadIdx.x;
    if (i < e) {
        int d = dst[i];
        int pos = atomicAdd(&cursor[d], 1);
        csr_src[pos] = src[i];
    }
}

// ---------------- fp32 tiled GEMM: C[M,128] = act(A[M,128]) @ W[128,128] ----------------
template <bool APPLY_BN, bool OUT_BIAS_RELU>
__global__ void k_gemm(const float* __restrict__ A, const float* __restrict__ W,
                       const float* __restrict__ bias,
                       const float* __restrict__ aff_a, const float* __restrict__ aff_b,
                       float* __restrict__ C, int M) {
    __shared__ float As[32][64];    // [k][m]
    __shared__ float Bs[32][128];   // [k][n]
    const int tid = threadIdx.x;
    const int tx = tid & 31;   // col group (4 cols)
    const int ty = tid >> 5;   // row group (8 rows)
    const int row0 = blockIdx.x * 64;

    float acc[8][4];
    #pragma unroll
    for (int i = 0; i < 8; ++i)
        #pragma unroll
        for (int j = 0; j < 4; ++j) acc[i][j] = 0.0f;

    for (int k0 = 0; k0 < HD; k0 += 32) {
        #pragma unroll
        for (int it = 0; it < 2; ++it) {
            int idx = tid + it * 256;          // 0..511
            int m = idx >> 3;
            int k4 = (idx & 7) << 2;
            int gm = row0 + m;
            float4 v = make_float4(0.f, 0.f, 0.f, 0.f);
            if (gm < M) v = ld4(A + (size_t)gm * HD + k0 + k4);
            if (APPLY_BN) {
                float4 a4 = ld4(aff_a + k0 + k4);
                float4 b4 = ld4(aff_b + k0 + k4);
                v.x = fmaxf(fmaf(v.x, a4.x, b4.x), 0.f);
                v.y = fmaxf(fmaf(v.y, a4.y, b4.y), 0.f);
                v.z = fmaxf(fmaf(v.z, a4.z, b4.z), 0.f);
                v.w = fmaxf(fmaf(v.w, a4.w, b4.w), 0.f);
            }
            As[k4 + 0][m] = v.x; As[k4 + 1][m] = v.y;
            As[k4 + 2][m] = v.z; As[k4 + 3][m] = v.w;
        }
        #pragma unroll
        for (int it = 0; it < 4; ++it) {
            int idx = tid + it * 256;          // 0..1023
            int kk = idx >> 5;
            int n4 = (idx & 31) << 2;
            *reinterpret_cast<float4*>(&Bs[kk][n4]) = ld4(W + (size_t)(k0 + kk) * HD + n4);
        }
        __syncthreads();
        #pragma unroll
        for (int k = 0; k < 32; ++k) {
            float4 b4 = *reinterpret_cast<const float4*>(&Bs[k][tx * 4]);
            float4 a0 = *reinterpret_cast<const float4*>(&As[k][ty * 8]);
            float4 a1 = *reinterpret_cast<const float4*>(&As[k][ty * 8 + 4]);
            float a[8] = {a0.x, a0.y, a0.z, a0.w, a1.x, a1.y, a1.z, a1.w};
            float b[4] = {b4.x, b4.y, b4.z, b4.w};
            #pragma unroll
            for (int i = 0; i < 8; ++i)
                #pragma unroll
                for (int j = 0; j < 4; ++j)
                    acc[i][j] = fmaf(a[i], b[j], acc[i][j]);
        }
        __syncthreads();
    }
    #pragma unroll
    for (int i = 0; i < 8; ++i) {
        int gm = row0 + ty * 8 + i;
        if (gm < M) {
            float4 o = make_float4(acc[i][0], acc[i][1], acc[i][2], acc[i][3]);
            if (OUT_BIAS_RELU) {
                float4 bb = ld4(bias + tx * 4);
                o.x = fmaxf(o.x + bb.x, 0.f);
                o.y = fmaxf(o.y + bb.y, 0.f);
                o.z = fmaxf(o.z + bb.z, 0.f);
                o.w = fmaxf(o.w + bb.w, 0.f);
            }
            *reinterpret_cast<float4*>(C + (size_t)gm * HD + tx * 4) = o;
        }
    }
}

// ---------------- per-node aggregation + BN stats (wave-per-node, 4-wide MLP) ----------
// h_pre[n] = sum_{s in in(n)} hw[s]*dinv[s]*dinv[n] + hw[n]/deg[n] + bias
// 256 threads = 4 waves; one wave per node; edge loop unrolled 4x so each wave
// keeps 4 independent 512B row-gathers in flight (latency hiding).
#define NPB 8
__global__ void k_agg(const float* __restrict__ hw, const int* __restrict__ row_start,
                      const int* __restrict__ csr_src, const float* __restrict__ dinv,
                      const float* __restrict__ bias_row, float* __restrict__ h_pre,
                      float* __restrict__ colsum, float* __restrict__ colsumsq, int n) {
    const int tid = threadIdx.x;
    const int lane = tid & 63;     // feature pair index
    const int slot = tid >> 6;     // wave id 0..3
    const int n0 = blockIdx.x * (4 * NPB);
    const float2* __restrict__ hw2 = (const float2*)hw;
    float2* __restrict__ hp2 = (float2*)h_pre;
    const float2 bias2 = *((const float2*)bias_row + lane);

    float2 psum = make_float2(0.f, 0.f);
    float2 psq  = make_float2(0.f, 0.f);

    for (int nn = 0; nn < NPB; ++nn) {
        int node = n0 + nn * 4 + slot;
        if (node < n) {
            float dn = dinv[node];
            float2 own = hw2[(size_t)node * 64 + lane];
            float sn = dn * dn;
            float accx = fmaf(own.x, sn, bias2.x);
            float accy = fmaf(own.y, sn, bias2.y);
            const int jb = row_start[node], je = row_start[node + 1];
            int j = jb;
            // 4-wide unrolled gather: 4 independent rows in flight
            for (; j + 4 <= je; j += 4) {
                int s0 = csr_src[j + 0];
                int s1 = csr_src[j + 1];
                int s2 = csr_src[j + 2];
                int s3 = csr_src[j + 3];
                float w0 = dinv[s0] * dn;
                float w1 = dinv[s1] * dn;
                float w2 = dinv[s2] * dn;
                float w3 = dinv[s3] * dn;
                float2 v0 = hw2[(size_t)s0 * 64 + lane];
                float2 v1 = hw2[(size_t)s1 * 64 + lane];
                float2 v2 = hw2[(size_t)s2 * 64 + lane];
                float2 v3 = hw2[(size_t)s3 * 64 + lane];
                accx = fmaf(v0.x, w0, accx); accy = fmaf(v0.y, w0, accy);
                accx = fmaf(v1.x, w1, accx); accy = fmaf(v1.y, w1, accy);
                accx = fmaf(v2.x, w2, accx); accy = fmaf(v2.y, w2, accy);
                accx = fmaf(v3.x, w3, accx); accy = fmaf(v3.y, w3, accy);
            }
            for (; j < je; ++j) {
                int s = csr_src[j];
                float w = dinv[s] * dn;
                float2 v = hw2[(size_t)s * 64 + lane];
                accx = fmaf(v.x, w, accx);
                accy = fmaf(v.y, w, accy);
            }
            hp2[(size_t)node * 64 + lane] = make_float2(accx, accy);
            psum.x += accx; psum.y += accy;
            psq.x = fmaf(accx, accx, psq.x);
            psq.y = fmaf(accy, accy, psq.y);
        }
    }

    // reduce the 4 slots in LDS, then 128 atomics per block
    __shared__ float2 redA[256];
    __shared__ float2 redB[256];
    redA[tid] = psum;
    redB[tid] = psq;
    __syncthreads();
    if (slot == 0) {
        #pragma unroll
        for (int s = 1; s < 4; ++s) {
            float2 a = redA[lane + s * 64], b = redB[lane + s * 64];
            psum.x += a.x; psum.y += a.y;
            psq.x += b.x;  psq.y += b.y;
        }
        atomicAdd(&colsum[lane * 2 + 0], psum.x);
        atomicAdd(&colsum[lane * 2 + 1], psum.y);
        atomicAdd(&colsumsq[lane * 2 + 0], psq.x);
        atomicAdd(&colsumsq[lane * 2 + 1], psq.y);
    }
}

// ---------------- BN coefficients (+ reset accumulators for next layer) ----------------
__global__ void k_bncoef(float* __restrict__ colsum, float* __restrict__ colsumsq,
                         const float* __restrict__ gamma, const float* __restrict__ beta,
                         float* __restrict__ aff_a, float* __restrict__ aff_b, int n) {
    int f = threadIdx.x;
    float inv_n = 1.0f / (float)n;
    float mean = colsum[f] * inv_n;
    float var = colsumsq[f] * inv_n - mean * mean;
    float rstd = 1.0f / sqrtf(var + EPS);
    float a = gamma[f] * rstd;
    aff_a[f] = a;
    aff_b[f] = beta[f] - mean * a;
    colsum[f] = 0.f;
    colsumsq[f] = 0.f;
}

// ---------------- graph boundaries (batch sorted) ----------------
__global__ void k_gbounds(const int* __restrict__ batch, int* __restrict__ gstart,
                          int n, int g) {
    int gi = blockIdx.x * blockDim.x + threadIdx.x;
    if (gi > g) return;
    int lo = 0, hi = n;
    while (lo < hi) {
        int mid = (lo + hi) >> 1;
        if (batch[mid] < gi) lo = mid + 1; else hi = mid;
    }
    gstart[gi] = lo;
}

// ---------------- per-graph mean pool with fused BN+relu (float2, 2 half-waves) --------
__global__ void k_pool(const float* __restrict__ h_pre, const int* __restrict__ gstart,
                       const float* __restrict__ aff_a, const float* __restrict__ aff_b,
                       float* __restrict__ pooled) {
    const int gi = blockIdx.x;
    const int tid = threadIdx.x;
    const int lane = tid & 63;
    const int half = tid >> 6;          // 0/1: alternate rows
    const float2* __restrict__ h2 = (const float2*)h_pre;
    const float2 a2 = *((const float2*)aff_a + lane);
    const float2 b2 = *((const float2*)aff_b + lane);
    int s = gstart[gi], e = gstart[gi + 1];
    float2 sum = make_float2(0.f, 0.f);
    for (int i = s + half; i < e; i += 2) {
        float2 v = h2[(size_t)i * 64 + lane];
        sum.x += fmaxf(fmaf(v.x, a2.x, b2.x), 0.f);
        sum.y += fmaxf(fmaf(v.y, a2.y, b2.y), 0.f);
    }
    __shared__ float2 red[128];
    red[tid] = sum;
    __syncthreads();
    if (half == 0) {
        float2 o = red[tid + 64];
        sum.x += o.x; sum.y += o.y;
        float inv = 1.0f / fmaxf((float)(e - s), 1.0f);
        float2* p2 = (float2*)pooled;
        p2[(size_t)gi * 64 + lane] = make_float2(sum.x * inv, sum.y * inv);
    }
}

// ---------------- head MLP: out = relu(p@W1+b1)@W2+b2 ----------------
__global__ void k_head(const float* __restrict__ pooled, const float* __restrict__ W1,
                       const float* __restrict__ b1, const float* __restrict__ W2,
                       const float* __restrict__ b2, float* __restrict__ out) {
    __shared__ float p[HD];
    __shared__ float t[HD];
    int gi = blockIdx.x;
    int j = threadIdx.x;
    p[j] = pooled[(size_t)gi * HD + j];
    __syncthreads();
    float acc = b1[j];
    #pragma unroll 8
    for (int k = 0; k < HD; ++k) acc = fmaf(p[k], W1[(size_t)k * HD + j], acc);
    t[j] = fmaxf(acc, 0.f);
    __syncthreads();
    if (j < EMB) {
        float o = b2[j];
        #pragma unroll 8
        for (int k = 0; k < HD; ++k) o = fmaf(t[k], W2[(size_t)k * EMB + j], o);
        out[(size_t)gi * EMB + j] = o;
    }
}

extern "C" void kernel_launch(void* const* d_in, const int* in_sizes, int n_in,
                              void* d_out, int out_size, void* d_ws, size_t ws_size,
                              hipStream_t stream) {
    const float* x     = (const float*)d_in[0];
    const int*   ei    = (const int*)d_in[1];
    const int*   batch = (const int*)d_in[2];
    const float* W_in  = (const float*)d_in[3];
    const float* b_in  = (const float*)d_in[4];
    const float* Ws    = (const float*)d_in[5];
    const float* bs    = (const float*)d_in[6];
    const float* gam   = (const float*)d_in[7];
    const float* bet   = (const float*)d_in[8];
    const float* W1    = (const float*)d_in[9];
    const float* b1    = (const float*)d_in[10];
    const float* W2    = (const float*)d_in[11];
    const float* b2    = (const float*)d_in[12];
    float* out = (float*)d_out;

    const int n = in_sizes[0] / HD;   // 100000
    const int e = in_sizes[1] / 2;    // 1600000
    const int g = out_size / EMB;     // 1024

    const int* esrc = ei;
    const int* edst = ei + e;

    // ---- workspace carve (256B aligned) ----
    char* w = (char*)d_ws;
    auto alloc = [&](size_t bytes) {
        char* p = w;
        w += (bytes + 255) & ~(size_t)255;
        return p;
    };
    float* hbuf    = (float*)alloc((size_t)n * HD * 4);
    float* hw      = (float*)alloc((size_t)n * HD * 4);
    int*   csr_src = (int*)alloc((size_t)e * 4);
    int*   deg     = (int*)alloc((size_t)n * 4);
    float* dinv    = (float*)alloc((size_t)n * 4);
    int*   rstart  = (int*)alloc((size_t)(n + 1) * 4);
    int*   cursor  = (int*)alloc((size_t)n * 4);
    int*   bsum    = (int*)alloc(512 * 4);
    float* colsum  = (float*)alloc(256 * 4);
    float* colsumsq = colsum + HD;
    float* aff_a   = (float*)alloc(256 * 4);
    float* aff_b   = aff_a + HD;
    int*   gstart  = (int*)alloc((size_t)(g + 1) * 4);
    float* pooled  = (float*)alloc((size_t)g * HD * 4);

    hipMemsetAsync(deg, 0, (size_t)n * 4, stream);
    hipMemsetAsync(colsum, 0, 256 * 4, stream);

    const int eb = (e + 255) / 256;
    const int nb = (n + 255) / 256;

    k_hist<<<eb, 256, 0, stream>>>(edst, deg, e);
    k_dinv<<<nb, 256, 0, stream>>>(deg, dinv, n);
    k_scan_part<<<nb, 256, 0, stream>>>(deg, rstart, bsum, n);
    k_scan_mid<<<1, 512, 0, stream>>>(bsum, nb);
    k_scan_add<<<nb, 256, 0, stream>>>(rstart, bsum, n, e);
    hipMemcpyAsync(cursor, rstart, (size_t)n * 4, hipMemcpyDeviceToDevice, stream);
    k_scatter<<<eb, 256, 0, stream>>>(esrc, edst, cursor, csr_src, e);

    const int gb = (n + 63) / 64;
    // input projection: h = relu(x @ W_in + b_in)
    k_gemm<false, true><<<gb, 256, 0, stream>>>(x, W_in, b_in, nullptr, nullptr, hbuf, n);

    const int ab = (n + 4 * NPB - 1) / (4 * NPB);
    for (int i = 0; i < 3; ++i) {
        if (i == 0)
            k_gemm<false, false><<<gb, 256, 0, stream>>>(
                hbuf, Ws + (size_t)i * HD * HD, nullptr, nullptr, nullptr, hw, n);
        else
            k_gemm<true, false><<<gb, 256, 0, stream>>>(
                hbuf, Ws + (size_t)i * HD * HD, nullptr, aff_a, aff_b, hw, n);
        k_agg<<<ab, 256, 0, stream>>>(hw, rstart, csr_src, dinv, bs + (size_t)i * HD,
                                      hbuf, colsum, colsumsq, n);
        k_bncoef<<<1, HD, 0, stream>>>(colsum, colsumsq, gam + (size_t)i * HD,
                                       bet + (size_t)i * HD, aff_a, aff_b, n);
    }

    k_gbounds<<<(g + 256) / 256, 256, 0, stream>>>(batch, gstart, n, g);
    k_pool<<<g, 128, 0, stream>>>(hbuf, gstart, aff_a, aff_b, pooled);
    k_head<<<g, HD, 0, stream>>>(pooled, W1, b1, W2, b2, out);
}

// Round 6
// 1175.123 us; speedup vs baseline: 1.0865x; 1.0756x over previous
//
#include <hip/hip_runtime.h>

#define HD 128
#define EMB 64
#define EPS 1e-5f

__device__ __forceinline__ float4 ld4(const float* p) {
    return *reinterpret_cast<const float4*>(p);
}

// float -> bf16 with round-to-nearest-even
__device__ __forceinline__ unsigned short f2bf(float f) {
    unsigned u = __float_as_uint(f);
    u += 0x7FFF + ((u >> 16) & 1);
    return (unsigned short)(u >> 16);
}
__device__ __forceinline__ float bf2f(unsigned short b) {
    return __uint_as_float((unsigned)b << 16);
}

// ---------------- degree histogram ----------------
__global__ void k_hist(const int* __restrict__ dst, int* __restrict__ deg, int e) {
    int i = blockIdx.x * blockDim.x + threadIdx.x;
    if (i < e) atomicAdd(&deg[dst[i]], 1);
}

__global__ void k_dinv(const int* __restrict__ deg, float* __restrict__ dinv, int n) {
    int i = blockIdx.x * blockDim.x + threadIdx.x;
    if (i < n) dinv[i] = 1.0f / sqrtf((float)deg[i] + 1.0f);
}

// ---------------- exclusive scan (3-phase) ----------------
__global__ void k_scan_part(const int* __restrict__ deg, int* __restrict__ out,
                            int* __restrict__ bsum, int n) {
    __shared__ int s[256];
    int i = blockIdx.x * 256 + threadIdx.x;
    int v = (i < n) ? deg[i] : 0;
    s[threadIdx.x] = v;
    __syncthreads();
    #pragma unroll
    for (int off = 1; off < 256; off <<= 1) {
        int t = (threadIdx.x >= off) ? s[threadIdx.x - off] : 0;
        __syncthreads();
        s[threadIdx.x] += t;
        __syncthreads();
    }
    if (i < n) out[i] = s[threadIdx.x] - v;         // exclusive
    if (threadIdx.x == 255) bsum[blockIdx.x] = s[255];
}

__global__ void k_scan_mid(int* __restrict__ bsum, int nb) {
    __shared__ int s[512];
    int t = threadIdx.x;
    int v = (t < nb) ? bsum[t] : 0;
    s[t] = v;
    __syncthreads();
    for (int off = 1; off < 512; off <<= 1) {
        int u = (t >= off) ? s[t - off] : 0;
        __syncthreads();
        s[t] += u;
        __syncthreads();
    }
    if (t < nb) bsum[t] = s[t] - v;                 // exclusive block offsets
}

__global__ void k_scan_add(int* __restrict__ rs, const int* __restrict__ bsum,
                           int n, int e_total) {
    int i = blockIdx.x * 256 + threadIdx.x;
    if (i < n) rs[i] += bsum[blockIdx.x];
    if (i == 0) rs[n] = e_total;
}

// ---------------- CSR scatter ----------------
__global__ void k_scatter(const int* __restrict__ src, const int* __restrict__ dst,
                          int* __restrict__ cursor, int* __restrict__ csr_src, int e) {
    int i = blockIdx.x * blockDim.x + threadIdx.x;
    if (i < e) {
        int d = dst[i];
        int pos = atomicAdd(&cursor[d], 1);
        csr_src[pos] = src[i];
    }
}

// ---------------- fp32 tiled GEMM: C[M,128] = act(A[M,128]) @ W[128,128] ----------------
// OUT_BF16: write C as bf16 (for the gather table), else fp32.
template <bool APPLY_BN, bool OUT_BIAS_RELU, bool OUT_BF16>
__global__ void k_gemm(const float* __restrict__ A, const float* __restrict__ W,
                       const float* __restrict__ bias,
                       const float* __restrict__ aff_a, const float* __restrict__ aff_b,
                       void* __restrict__ Cout, int M) {
    __shared__ float As[32][64];    // [k][m]
    __shared__ float Bs[32][128];   // [k][n]
    const int tid = threadIdx.x;
    const int tx = tid & 31;   // col group (4 cols)
    const int ty = tid >> 5;   // row group (8 rows)
    const int row0 = blockIdx.x * 64;

    float acc[8][4];
    #pragma unroll
    for (int i = 0; i < 8; ++i)
        #pragma unroll
        for (int j = 0; j < 4; ++j) acc[i][j] = 0.0f;

    for (int k0 = 0; k0 < HD; k0 += 32) {
        #pragma unroll
        for (int it = 0; it < 2; ++it) {
            int idx = tid + it * 256;          // 0..511
            int m = idx >> 3;
            int k4 = (idx & 7) << 2;
            int gm = row0 + m;
            float4 v = make_float4(0.f, 0.f, 0.f, 0.f);
            if (gm < M) v = ld4(A + (size_t)gm * HD + k0 + k4);
            if (APPLY_BN) {
                float4 a4 = ld4(aff_a + k0 + k4);
                float4 b4 = ld4(aff_b + k0 + k4);
                v.x = fmaxf(fmaf(v.x, a4.x, b4.x), 0.f);
                v.y = fmaxf(fmaf(v.y, a4.y, b4.y), 0.f);
                v.z = fmaxf(fmaf(v.z, a4.z, b4.z), 0.f);
                v.w = fmaxf(fmaf(v.w, a4.w, b4.w), 0.f);
            }
            As[k4 + 0][m] = v.x; As[k4 + 1][m] = v.y;
            As[k4 + 2][m] = v.z; As[k4 + 3][m] = v.w;
        }
        #pragma unroll
        for (int it = 0; it < 4; ++it) {
            int idx = tid + it * 256;          // 0..1023
            int kk = idx >> 5;
            int n4 = (idx & 31) << 2;
            *reinterpret_cast<float4*>(&Bs[kk][n4]) = ld4(W + (size_t)(k0 + kk) * HD + n4);
        }
        __syncthreads();
        #pragma unroll
        for (int k = 0; k < 32; ++k) {
            float4 b4 = *reinterpret_cast<const float4*>(&Bs[k][tx * 4]);
            float4 a0 = *reinterpret_cast<const float4*>(&As[k][ty * 8]);
            float4 a1 = *reinterpret_cast<const float4*>(&As[k][ty * 8 + 4]);
            float a[8] = {a0.x, a0.y, a0.z, a0.w, a1.x, a1.y, a1.z, a1.w};
            float b[4] = {b4.x, b4.y, b4.z, b4.w};
            #pragma unroll
            for (int i = 0; i < 8; ++i)
                #pragma unroll
                for (int j = 0; j < 4; ++j)
                    acc[i][j] = fmaf(a[i], b[j], acc[i][j]);
        }
        __syncthreads();
    }
    #pragma unroll
    for (int i = 0; i < 8; ++i) {
        int gm = row0 + ty * 8 + i;
        if (gm < M) {
            float4 o = make_float4(acc[i][0], acc[i][1], acc[i][2], acc[i][3]);
            if (OUT_BIAS_RELU) {
                float4 bb = ld4(bias + tx * 4);
                o.x = fmaxf(o.x + bb.x, 0.f);
                o.y = fmaxf(o.y + bb.y, 0.f);
                o.z = fmaxf(o.z + bb.z, 0.f);
                o.w = fmaxf(o.w + bb.w, 0.f);
            }
            if (OUT_BF16) {
                unsigned short b0 = f2bf(o.x), b1 = f2bf(o.y),
                               b2 = f2bf(o.z), b3 = f2bf(o.w);
                uint2 pk;
                pk.x = (unsigned)b0 | ((unsigned)b1 << 16);
                pk.y = (unsigned)b2 | ((unsigned)b3 << 16);
                *reinterpret_cast<uint2*>((unsigned short*)Cout + (size_t)gm * HD + tx * 4) = pk;
            } else {
                *reinterpret_cast<float4*>((float*)Cout + (size_t)gm * HD + tx * 4) = o;
            }
        }
    }
}

// ---------------- per-node aggregation + BN stats (bf16 gather table) ----------------
// h_pre[n] = sum_{s in in(n)} hw[s]*dinv[s]*dinv[n] + hw[n]/deg[n] + bias
// 256 threads = 4 waves; one wave per node; lane holds 2 features (ushort2 = 4B/lane,
// 256B per gathered row). Edge loop unrolled 4x.
#define NPB 8
__global__ void k_agg(const unsigned short* __restrict__ hw, const int* __restrict__ row_start,
                      const int* __restrict__ csr_src, const float* __restrict__ dinv,
                      const float* __restrict__ bias_row, float* __restrict__ h_pre,
                      float* __restrict__ colsum, float* __restrict__ colsumsq, int n) {
    const int tid = threadIdx.x;
    const int lane = tid & 63;     // feature pair index
    const int slot = tid >> 6;     // wave id 0..3
    const int n0 = blockIdx.x * (4 * NPB);
    const ushort2* __restrict__ hw2 = (const ushort2*)hw;
    float2* __restrict__ hp2 = (float2*)h_pre;
    const float2 bias2 = *((const float2*)bias_row + lane);

    float2 psum = make_float2(0.f, 0.f);
    float2 psq  = make_float2(0.f, 0.f);

    for (int nn = 0; nn < NPB; ++nn) {
        int node = n0 + nn * 4 + slot;
        if (node < n) {
            float dn = dinv[node];
            ushort2 ow = hw2[(size_t)node * 64 + lane];
            float sn = dn * dn;
            float accx = fmaf(bf2f(ow.x), sn, bias2.x);
            float accy = fmaf(bf2f(ow.y), sn, bias2.y);
            const int jb = row_start[node], je = row_start[node + 1];
            int j = jb;
            for (; j + 4 <= je; j += 4) {
                int s0 = csr_src[j + 0];
                int s1 = csr_src[j + 1];
                int s2 = csr_src[j + 2];
                int s3 = csr_src[j + 3];
                float w0 = dinv[s0] * dn;
                float w1 = dinv[s1] * dn;
                float w2 = dinv[s2] * dn;
                float w3 = dinv[s3] * dn;
                ushort2 v0 = hw2[(size_t)s0 * 64 + lane];
                ushort2 v1 = hw2[(size_t)s1 * 64 + lane];
                ushort2 v2 = hw2[(size_t)s2 * 64 + lane];
                ushort2 v3 = hw2[(size_t)s3 * 64 + lane];
                accx = fmaf(bf2f(v0.x), w0, accx); accy = fmaf(bf2f(v0.y), w0, accy);
                accx = fmaf(bf2f(v1.x), w1, accx); accy = fmaf(bf2f(v1.y), w1, accy);
                accx = fmaf(bf2f(v2.x), w2, accx); accy = fmaf(bf2f(v2.y), w2, accy);
                accx = fmaf(bf2f(v3.x), w3, accx); accy = fmaf(bf2f(v3.y), w3, accy);
            }
            for (; j < je; ++j) {
                int s = csr_src[j];
                float w = dinv[s] * dn;
                ushort2 v = hw2[(size_t)s * 64 + lane];
                accx = fmaf(bf2f(v.x), w, accx);
                accy = fmaf(bf2f(v.y), w, accy);
            }
            hp2[(size_t)node * 64 + lane] = make_float2(accx, accy);
            psum.x += accx; psum.y += accy;
            psq.x = fmaf(accx, accx, psq.x);
            psq.y = fmaf(accy, accy, psq.y);
        }
    }

    __shared__ float2 redA[256];
    __shared__ float2 redB[256];
    redA[tid] = psum;
    redB[tid] = psq;
    __syncthreads();
    if (slot == 0) {
        #pragma unroll
        for (int s = 1; s < 4; ++s) {
            float2 a = redA[lane + s * 64], b = redB[lane + s * 64];
            psum.x += a.x; psum.y += a.y;
            psq.x += b.x;  psq.y += b.y;
        }
        atomicAdd(&colsum[lane * 2 + 0], psum.x);
        atomicAdd(&colsum[lane * 2 + 1], psum.y);
        atomicAdd(&colsumsq[lane * 2 + 0], psq.x);
        atomicAdd(&colsumsq[lane * 2 + 1], psq.y);
    }
}

// ---------------- BN coefficients (+ reset accumulators for next layer) ----------------
__global__ void k_bncoef(float* __restrict__ colsum, float* __restrict__ colsumsq,
                         const float* __restrict__ gamma, const float* __restrict__ beta,
                         float* __restrict__ aff_a, float* __restrict__ aff_b, int n) {
    int f = threadIdx.x;
    float inv_n = 1.0f / (float)n;
    float mean = colsum[f] * inv_n;
    float var = colsumsq[f] * inv_n - mean * mean;
    float rstd = 1.0f / sqrtf(var + EPS);
    float a = gamma[f] * rstd;
    aff_a[f] = a;
    aff_b[f] = beta[f] - mean * a;
    colsum[f] = 0.f;
    colsumsq[f] = 0.f;
}

// ---------------- graph boundaries (batch sorted) ----------------
__global__ void k_gbounds(const int* __restrict__ batch, int* __restrict__ gstart,
                          int n, int g) {
    int gi = blockIdx.x * blockDim.x + threadIdx.x;
    if (gi > g) return;
    int lo = 0, hi = n;
    while (lo < hi) {
        int mid = (lo + hi) >> 1;
        if (batch[mid] < gi) lo = mid + 1; else hi = mid;
    }
    gstart[gi] = lo;
}

// ---------------- per-graph mean pool with fused BN+relu (float2, 2 half-waves) --------
__global__ void k_pool(const float* __restrict__ h_pre, const int* __restrict__ gstart,
                       const float* __restrict__ aff_a, const float* __restrict__ aff_b,
                       float* __restrict__ pooled) {
    const int gi = blockIdx.x;
    const int tid = threadIdx.x;
    const int lane = tid & 63;
    const int half = tid >> 6;          // 0/1: alternate rows
    const float2* __restrict__ h2 = (const float2*)h_pre;
    const float2 a2 = *((const float2*)aff_a + lane);
    const float2 b2 = *((const float2*)aff_b + lane);
    int s = gstart[gi], e = gstart[gi + 1];
    float2 sum = make_float2(0.f, 0.f);
    for (int i = s + half; i < e; i += 2) {
        float2 v = h2[(size_t)i * 64 + lane];
        sum.x += fmaxf(fmaf(v.x, a2.x, b2.x), 0.f);
        sum.y += fmaxf(fmaf(v.y, a2.y, b2.y), 0.f);
    }
    __shared__ float2 red[128];
    red[tid] = sum;
    __syncthreads();
    if (half == 0) {
        float2 o = red[tid + 64];
        sum.x += o.x; sum.y += o.y;
        float inv = 1.0f / fmaxf((float)(e - s), 1.0f);
        float2* p2 = (float2*)pooled;
        p2[(size_t)gi * 64 + lane] = make_float2(sum.x * inv, sum.y * inv);
    }
}

// ---------------- head MLP: out = relu(p@W1+b1)@W2+b2 ----------------
__global__ void k_head(const float* __restrict__ pooled, const float* __restrict__ W1,
                       const float* __restrict__ b1, const float* __restrict__ W2,
                       const float* __restrict__ b2, float* __restrict__ out) {
    __shared__ float p[HD];
    __shared__ float t[HD];
    int gi = blockIdx.x;
    int j = threadIdx.x;
    p[j] = pooled[(size_t)gi * HD + j];
    __syncthreads();
    float acc = b1[j];
    #pragma unroll 8
    for (int k = 0; k < HD; ++k) acc = fmaf(p[k], W1[(size_t)k * HD + j], acc);
    t[j] = fmaxf(acc, 0.f);
    __syncthreads();
    if (j < EMB) {
        float o = b2[j];
        #pragma unroll 8
        for (int k = 0; k < HD; ++k) o = fmaf(t[k], W2[(size_t)k * EMB + j], o);
        out[(size_t)gi * EMB + j] = o;
    }
}

extern "C" void kernel_launch(void* const* d_in, const int* in_sizes, int n_in,
                              void* d_out, int out_size, void* d_ws, size_t ws_size,
                              hipStream_t stream) {
    const float* x     = (const float*)d_in[0];
    const int*   ei    = (const int*)d_in[1];
    const int*   batch = (const int*)d_in[2];
    const float* W_in  = (const float*)d_in[3];
    const float* b_in  = (const float*)d_in[4];
    const float* Ws    = (const float*)d_in[5];
    const float* bs    = (const float*)d_in[6];
    const float* gam   = (const float*)d_in[7];
    const float* bet   = (const float*)d_in[8];
    const float* W1    = (const float*)d_in[9];
    const float* b1    = (const float*)d_in[10];
    const float* W2    = (const float*)d_in[11];
    const float* b2    = (const float*)d_in[12];
    float* out = (float*)d_out;

    const int n = in_sizes[0] / HD;   // 100000
    const int e = in_sizes[1] / 2;    // 1600000
    const int g = out_size / EMB;     // 1024

    const int* esrc = ei;
    const int* edst = ei + e;

    // ---- workspace carve (256B aligned) ----
    char* w = (char*)d_ws;
    auto alloc = [&](size_t bytes) {
        char* p = w;
        w += (bytes + 255) & ~(size_t)255;
        return p;
    };
    float* hbuf             = (float*)alloc((size_t)n * HD * 4);
    unsigned short* hw      = (unsigned short*)alloc((size_t)n * HD * 2);  // bf16 gather table
    int*   csr_src = (int*)alloc((size_t)e * 4);
    int*   deg     = (int*)alloc((size_t)n * 4);
    float* dinv    = (float*)alloc((size_t)n * 4);
    int*   rstart  = (int*)alloc((size_t)(n + 1) * 4);
    int*   cursor  = (int*)alloc((size_t)n * 4);
    int*   bsum    = (int*)alloc(512 * 4);
    float* colsum  = (float*)alloc(256 * 4);
    float* colsumsq = colsum + HD;
    float* aff_a   = (float*)alloc(256 * 4);
    float* aff_b   = aff_a + HD;
    int*   gstart  = (int*)alloc((size_t)(g + 1) * 4);
    float* pooled  = (float*)alloc((size_t)g * HD * 4);

    hipMemsetAsync(deg, 0, (size_t)n * 4, stream);
    hipMemsetAsync(colsum, 0, 256 * 4, stream);

    const int eb = (e + 255) / 256;
    const int nb = (n + 255) / 256;

    k_hist<<<eb, 256, 0, stream>>>(edst, deg, e);
    k_dinv<<<nb, 256, 0, stream>>>(deg, dinv, n);
    k_scan_part<<<nb, 256, 0, stream>>>(deg, rstart, bsum, n);
    k_scan_mid<<<1, 512, 0, stream>>>(bsum, nb);
    k_scan_add<<<nb, 256, 0, stream>>>(rstart, bsum, n, e);
    hipMemcpyAsync(cursor, rstart, (size_t)n * 4, hipMemcpyDeviceToDevice, stream);
    k_scatter<<<eb, 256, 0, stream>>>(esrc, edst, cursor, csr_src, e);

    const int gb = (n + 63) / 64;
    // input projection: h = relu(x @ W_in + b_in)  (fp32 out)
    k_gemm<false, true, false><<<gb, 256, 0, stream>>>(x, W_in, b_in, nullptr, nullptr, hbuf, n);

    const int ab = (n + 4 * NPB - 1) / (4 * NPB);
    for (int i = 0; i < 3; ++i) {
        if (i == 0)
            k_gemm<false, false, true><<<gb, 256, 0, stream>>>(
                hbuf, Ws + (size_t)i * HD * HD, nullptr, nullptr, nullptr, hw, n);
        else
            k_gemm<true, false, true><<<gb, 256, 0, stream>>>(
                hbuf, Ws + (size_t)i * HD * HD, nullptr, aff_a, aff_b, hw, n);
        k_agg<<<ab, 256, 0, stream>>>(hw, rstart, csr_src, dinv, bs + (size_t)i * HD,
                                      hbuf, colsum, colsumsq, n);
        k_bncoef<<<1, HD, 0, stream>>>(colsum, colsumsq, gam + (size_t)i * HD,
                                       bet + (size_t)i * HD, aff_a, aff_b, n);
    }

    k_gbounds<<<(g + 256) / 256, 256, 0, stream>>>(batch, gstart, n, g);
    k_pool<<<g, 128, 0, stream>>>(hbuf, gstart, aff_a, aff_b, pooled);
    k_head<<<g, HD, 0, stream>>>(pooled, W1, b1, W2, b2, out);
}

// Round 7
// 945.824 us; speedup vs baseline: 1.3499x; 1.2424x over previous
//
#include <hip/hip_runtime.h>

#define HD 128
#define EMB 64
#define EPS 1e-5f

__device__ __forceinline__ float4 ld4(const float* p) {
    return *reinterpret_cast<const float4*>(p);
}

// float -> bf16 with round-to-nearest-even
__device__ __forceinline__ unsigned short f2bf(float f) {
    unsigned u = __float_as_uint(f);
    u += 0x7FFF + ((u >> 16) & 1);
    return (unsigned short)(u >> 16);
}
__device__ __forceinline__ float bf2f(unsigned short b) {
    return __uint_as_float((unsigned)b << 16);
}
// bf16 pair unpack from packed u32 (elem0 = low 16 bits)
__device__ __forceinline__ float blo(unsigned u) { return __uint_as_float(u << 16); }
__device__ __forceinline__ float bhi(unsigned u) { return __uint_as_float(u & 0xffff0000u); }

// ---------------- degree histogram ----------------
__global__ void k_hist(const int* __restrict__ dst, int* __restrict__ deg, int e) {
    int i = blockIdx.x * blockDim.x + threadIdx.x;
    if (i < e) atomicAdd(&deg[dst[i]], 1);
}

__global__ void k_dinv(const int* __restrict__ deg, float* __restrict__ dinv, int n) {
    int i = blockIdx.x * blockDim.x + threadIdx.x;
    if (i < n) dinv[i] = 1.0f / sqrtf((float)deg[i] + 1.0f);
}

// ---------------- exclusive scan (3-phase) ----------------
__global__ void k_scan_part(const int* __restrict__ deg, int* __restrict__ out,
                            int* __restrict__ bsum, int n) {
    __shared__ int s[256];
    int i = blockIdx.x * 256 + threadIdx.x;
    int v = (i < n) ? deg[i] : 0;
    s[threadIdx.x] = v;
    __syncthreads();
    #pragma unroll
    for (int off = 1; off < 256; off <<= 1) {
        int t = (threadIdx.x >= off) ? s[threadIdx.x - off] : 0;
        __syncthreads();
        s[threadIdx.x] += t;
        __syncthreads();
    }
    if (i < n) out[i] = s[threadIdx.x] - v;         // exclusive
    if (threadIdx.x == 255) bsum[blockIdx.x] = s[255];
}

__global__ void k_scan_mid(int* __restrict__ bsum, int nb) {
    __shared__ int s[512];
    int t = threadIdx.x;
    int v = (t < nb) ? bsum[t] : 0;
    s[t] = v;
    __syncthreads();
    for (int off = 1; off < 512; off <<= 1) {
        int u = (t >= off) ? s[t - off] : 0;
        __syncthreads();
        s[t] += u;
        __syncthreads();
    }
    if (t < nb) bsum[t] = s[t] - v;                 // exclusive block offsets
}

__global__ void k_scan_add(int* __restrict__ rs, const int* __restrict__ bsum,
                           int n, int e_total) {
    int i = blockIdx.x * 256 + threadIdx.x;
    if (i < n) rs[i] += bsum[blockIdx.x];
    if (i == 0) rs[n] = e_total;
}

// ---------------- CSR scatter ----------------
__global__ void k_scatter(const int* __restrict__ src, const int* __restrict__ dst,
                          int* __restrict__ cursor, int* __restrict__ csr_src, int e) {
    int i = blockIdx.x * blockDim.x + threadIdx.x;
    if (i < e) {
        int d = dst[i];
        int pos = atomicAdd(&cursor[d], 1);
        csr_src[pos] = src[i];
    }
}

// ---------------- fp32 tiled GEMM: C[M,128] = act(A[M,128]) @ W[128,128] ----------------
// OUT_BF16: write C as bf16 (for the gather table), else fp32.
template <bool APPLY_BN, bool OUT_BIAS_RELU, bool OUT_BF16>
__global__ void k_gemm(const float* __restrict__ A, const float* __restrict__ W,
                       const float* __restrict__ bias,
                       const float* __restrict__ aff_a, const float* __restrict__ aff_b,
                       void* __restrict__ Cout, int M) {
    __shared__ float As[32][64];    // [k][m]
    __shared__ float Bs[32][128];   // [k][n]
    const int tid = threadIdx.x;
    const int tx = tid & 31;   // col group (4 cols)
    const int ty = tid >> 5;   // row group (8 rows)
    const int row0 = blockIdx.x * 64;

    float acc[8][4];
    #pragma unroll
    for (int i = 0; i < 8; ++i)
        #pragma unroll
        for (int j = 0; j < 4; ++j) acc[i][j] = 0.0f;

    for (int k0 = 0; k0 < HD; k0 += 32) {
        #pragma unroll
        for (int it = 0; it < 2; ++it) {
            int idx = tid + it * 256;          // 0..511
            int m = idx >> 3;
            int k4 = (idx & 7) << 2;
            int gm = row0 + m;
            float4 v = make_float4(0.f, 0.f, 0.f, 0.f);
            if (gm < M) v = ld4(A + (size_t)gm * HD + k0 + k4);
            if (APPLY_BN) {
                float4 a4 = ld4(aff_a + k0 + k4);
                float4 b4 = ld4(aff_b + k0 + k4);
                v.x = fmaxf(fmaf(v.x, a4.x, b4.x), 0.f);
                v.y = fmaxf(fmaf(v.y, a4.y, b4.y), 0.f);
                v.z = fmaxf(fmaf(v.z, a4.z, b4.z), 0.f);
                v.w = fmaxf(fmaf(v.w, a4.w, b4.w), 0.f);
            }
            As[k4 + 0][m] = v.x; As[k4 + 1][m] = v.y;
            As[k4 + 2][m] = v.z; As[k4 + 3][m] = v.w;
        }
        #pragma unroll
        for (int it = 0; it < 4; ++it) {
            int idx = tid + it * 256;          // 0..1023
            int kk = idx >> 5;
            int n4 = (idx & 31) << 2;
            *reinterpret_cast<float4*>(&Bs[kk][n4]) = ld4(W + (size_t)(k0 + kk) * HD + n4);
        }
        __syncthreads();
        #pragma unroll
        for (int k = 0; k < 32; ++k) {
            float4 b4 = *reinterpret_cast<const float4*>(&Bs[k][tx * 4]);
            float4 a0 = *reinterpret_cast<const float4*>(&As[k][ty * 8]);
            float4 a1 = *reinterpret_cast<const float4*>(&As[k][ty * 8 + 4]);
            float a[8] = {a0.x, a0.y, a0.z, a0.w, a1.x, a1.y, a1.z, a1.w};
            float b[4] = {b4.x, b4.y, b4.z, b4.w};
            #pragma unroll
            for (int i = 0; i < 8; ++i)
                #pragma unroll
                for (int j = 0; j < 4; ++j)
                    acc[i][j] = fmaf(a[i], b[j], acc[i][j]);
        }
        __syncthreads();
    }
    #pragma unroll
    for (int i = 0; i < 8; ++i) {
        int gm = row0 + ty * 8 + i;
        if (gm < M) {
            float4 o = make_float4(acc[i][0], acc[i][1], acc[i][2], acc[i][3]);
            if (OUT_BIAS_RELU) {
                float4 bb = ld4(bias + tx * 4);
                o.x = fmaxf(o.x + bb.x, 0.f);
                o.y = fmaxf(o.y + bb.y, 0.f);
                o.z = fmaxf(o.z + bb.z, 0.f);
                o.w = fmaxf(o.w + bb.w, 0.f);
            }
            if (OUT_BF16) {
                unsigned short b0 = f2bf(o.x), b1 = f2bf(o.y),
                               b2 = f2bf(o.z), b3 = f2bf(o.w);
                uint2 pk;
                pk.x = (unsigned)b0 | ((unsigned)b1 << 16);
                pk.y = (unsigned)b2 | ((unsigned)b3 << 16);
                *reinterpret_cast<uint2*>((unsigned short*)Cout + (size_t)gm * HD + tx * 4) = pk;
            } else {
                *reinterpret_cast<float4*>((float*)Cout + (size_t)gm * HD + tx * 4) = o;
            }
        }
    }
}

// ---------------- per-node aggregation + BN stats (4 edges per gather instr) ----------
// h_pre[n] = sum_{s in in(n)} hw[s]*dinv[s]*dinv[n] + hw[n]/deg[n] + bias
// 256 threads = 4 waves; one wave per node. Wave split into 4 groups of 16 lanes:
// group g handles edge j+g; lane (g,q) loads uint4 = 8 bf16 features at slice q.
// One wave-instruction gathers FOUR 256B rows -> 4x fewer gather instructions.
// Cross-group combine via shfl_xor(16,32); 2-deep unroll = 8 edges in flight.
#define NPB 8
__global__ void k_agg(const unsigned short* __restrict__ hw, const int* __restrict__ row_start,
                      const int* __restrict__ csr_src, const float* __restrict__ dinv,
                      const float* __restrict__ bias_row, float* __restrict__ h_pre,
                      float* __restrict__ colsum, float* __restrict__ colsumsq, int n) {
    const int tid  = threadIdx.x;
    const int lane = tid & 63;
    const int slot = tid >> 6;       // wave id 0..3
    const int q    = lane & 15;      // 16B slice (features q*8 .. q*8+7)
    const int grp  = lane >> 4;      // edge group 0..3
    const int n0 = blockIdx.x * (4 * NPB);
    const uint4* __restrict__ hw4 = (const uint4*)hw;   // row = 16 x uint4

    float b8[8];
    #pragma unroll
    for (int k = 0; k < 8; ++k) b8[k] = bias_row[q * 8 + k];

    float psum8[8], psq8[8];
    #pragma unroll
    for (int k = 0; k < 8; ++k) { psum8[k] = 0.f; psq8[k] = 0.f; }

    for (int nn = 0; nn < NPB; ++nn) {
        int node = n0 + nn * 4 + slot;     // wave-uniform
        if (node >= n) continue;
        float dn = dinv[node];
        float acc[8];
        #pragma unroll
        for (int k = 0; k < 8; ++k) acc[k] = 0.f;

        const int jb = row_start[node], je = row_start[node + 1];
        for (int j = jb; j < je; j += 8) {
            int e0 = j + grp;
            int s0 = (e0 < je) ? csr_src[e0] : 0;
            float w0 = (e0 < je) ? dinv[s0] * dn : 0.f;
            uint4 r0 = hw4[(size_t)s0 * 16 + q];
            int e1 = j + 4 + grp;
            int s1 = (e1 < je) ? csr_src[e1] : 0;
            float w1 = (e1 < je) ? dinv[s1] * dn : 0.f;
            uint4 r1 = hw4[(size_t)s1 * 16 + q];

            acc[0] = fmaf(blo(r0.x), w0, acc[0]); acc[1] = fmaf(bhi(r0.x), w0, acc[1]);
            acc[2] = fmaf(blo(r0.y), w0, acc[2]); acc[3] = fmaf(bhi(r0.y), w0, acc[3]);
            acc[4] = fmaf(blo(r0.z), w0, acc[4]); acc[5] = fmaf(bhi(r0.z), w0, acc[5]);
            acc[6] = fmaf(blo(r0.w), w0, acc[6]); acc[7] = fmaf(bhi(r0.w), w0, acc[7]);

            acc[0] = fmaf(blo(r1.x), w1, acc[0]); acc[1] = fmaf(bhi(r1.x), w1, acc[1]);
            acc[2] = fmaf(blo(r1.y), w1, acc[2]); acc[3] = fmaf(bhi(r1.y), w1, acc[3]);
            acc[4] = fmaf(blo(r1.z), w1, acc[4]); acc[5] = fmaf(bhi(r1.z), w1, acc[5]);
            acc[6] = fmaf(blo(r1.w), w1, acc[6]); acc[7] = fmaf(bhi(r1.w), w1, acc[7]);
        }

        // combine the 4 edge-groups (each lane ends with full sum for its slice q)
        #pragma unroll
        for (int k = 0; k < 8; ++k) acc[k] += __shfl_xor(acc[k], 16, 64);
        #pragma unroll
        for (int k = 0; k < 8; ++k) acc[k] += __shfl_xor(acc[k], 32, 64);

        // self-loop term + bias
        uint4 ow = hw4[(size_t)node * 16 + q];
        float sn = dn * dn;
        acc[0] = fmaf(blo(ow.x), sn, acc[0] + b8[0]);
        acc[1] = fmaf(bhi(ow.x), sn, acc[1] + b8[1]);
        acc[2] = fmaf(blo(ow.y), sn, acc[2] + b8[2]);
        acc[3] = fmaf(bhi(ow.y), sn, acc[3] + b8[3]);
        acc[4] = fmaf(blo(ow.z), sn, acc[4] + b8[4]);
        acc[5] = fmaf(bhi(ow.z), sn, acc[5] + b8[5]);
        acc[6] = fmaf(blo(ow.w), sn, acc[6] + b8[6]);
        acc[7] = fmaf(bhi(ow.w), sn, acc[7] + b8[7]);

        if (grp == 0) {
            float* dst = h_pre + (size_t)node * HD + q * 8;
            *reinterpret_cast<float4*>(dst)     = make_float4(acc[0], acc[1], acc[2], acc[3]);
            *reinterpret_cast<float4*>(dst + 4) = make_float4(acc[4], acc[5], acc[6], acc[7]);
            #pragma unroll
            for (int k = 0; k < 8; ++k) {
                psum8[k] += acc[k];
                psq8[k] = fmaf(acc[k], acc[k], psq8[k]);
            }
        }
    }

    // block-level BN stats reduction: 4 slots x 128 features
    __shared__ float redS[4][128];
    __shared__ float redQ[4][128];
    if (grp == 0) {
        #pragma unroll
        for (int k = 0; k < 8; ++k) {
            redS[slot][q * 8 + k] = psum8[k];
            redQ[slot][q * 8 + k] = psq8[k];
        }
    }
    __syncthreads();
    int f = tid & 127;
    if (tid < 128) {
        float s = redS[0][f] + redS[1][f] + redS[2][f] + redS[3][f];
        atomicAdd(&colsum[f], s);
    } else {
        float s = redQ[0][f] + redQ[1][f] + redQ[2][f] + redQ[3][f];
        atomicAdd(&colsumsq[f], s);
    }
}

// ---------------- BN coefficients (+ reset accumulators for next layer) ----------------
__global__ void k_bncoef(float* __restrict__ colsum, float* __restrict__ colsumsq,
                         const float* __restrict__ gamma, const float* __restrict__ beta,
                         float* __restrict__ aff_a, float* __restrict__ aff_b, int n) {
    int f = threadIdx.x;
    float inv_n = 1.0f / (float)n;
    float mean = colsum[f] * inv_n;
    float var = colsumsq[f] * inv_n - mean * mean;
    float rstd = 1.0f / sqrtf(var + EPS);
    float a = gamma[f] * rstd;
    aff_a[f] = a;
    aff_b[f] = beta[f] - mean * a;
    colsum[f] = 0.f;
    colsumsq[f] = 0.f;
}

// ---------------- graph boundaries (batch sorted) ----------------
__global__ void k_gbounds(const int* __restrict__ batch, int* __restrict__ gstart,
                          int n, int g) {
    int gi = blockIdx.x * blockDim.x + threadIdx.x;
    if (gi > g) return;
    int lo = 0, hi = n;
    while (lo < hi) {
        int mid = (lo + hi) >> 1;
        if (batch[mid] < gi) lo = mid + 1; else hi = mid;
    }
    gstart[gi] = lo;
}

// ---------------- per-graph mean pool with fused BN+relu (float2, 2 half-waves) --------
__global__ void k_pool(const float* __restrict__ h_pre, const int* __restrict__ gstart,
                       const float* __restrict__ aff_a, const float* __restrict__ aff_b,
                       float* __restrict__ pooled) {
    const int gi = blockIdx.x;
    const int tid = threadIdx.x;
    const int lane = tid & 63;
    const int half = tid >> 6;          // 0/1: alternate rows
    const float2* __restrict__ h2 = (const float2*)h_pre;
    const float2 a2 = *((const float2*)aff_a + lane);
    const float2 b2 = *((const float2*)aff_b + lane);
    int s = gstart[gi], e = gstart[gi + 1];
    float2 sum = make_float2(0.f, 0.f);
    for (int i = s + half; i < e; i += 2) {
        float2 v = h2[(size_t)i * 64 + lane];
        sum.x += fmaxf(fmaf(v.x, a2.x, b2.x), 0.f);
        sum.y += fmaxf(fmaf(v.y, a2.y, b2.y), 0.f);
    }
    __shared__ float2 red[128];
    red[tid] = sum;
    __syncthreads();
    if (half == 0) {
        float2 o = red[tid + 64];
        sum.x += o.x; sum.y += o.y;
        float inv = 1.0f / fmaxf((float)(e - s), 1.0f);
        float2* p2 = (float2*)pooled;
        p2[(size_t)gi * 64 + lane] = make_float2(sum.x * inv, sum.y * inv);
    }
}

// ---------------- head MLP: out = relu(p@W1+b1)@W2+b2 ----------------
__global__ void k_head(const float* __restrict__ pooled, const float* __restrict__ W1,
                       const float* __restrict__ b1, const float* __restrict__ W2,
                       const float* __restrict__ b2, float* __restrict__ out) {
    __shared__ float p[HD];
    __shared__ float t[HD];
    int gi = blockIdx.x;
    int j = threadIdx.x;
    p[j] = pooled[(size_t)gi * HD + j];
    __syncthreads();
    float acc = b1[j];
    #pragma unroll 8
    for (int k = 0; k < HD; ++k) acc = fmaf(p[k], W1[(size_t)k * HD + j], acc);
    t[j] = fmaxf(acc, 0.f);
    __syncthreads();
    if (j < EMB) {
        float o = b2[j];
        #pragma unroll 8
        for (int k = 0; k < HD; ++k) o = fmaf(t[k], W2[(size_t)k * EMB + j], o);
        out[(size_t)gi * EMB + j] = o;
    }
}

extern "C" void kernel_launch(void* const* d_in, const int* in_sizes, int n_in,
                              void* d_out, int out_size, void* d_ws, size_t ws_size,
                              hipStream_t stream) {
    const float* x     = (const float*)d_in[0];
    const int*   ei    = (const int*)d_in[1];
    const int*   batch = (const int*)d_in[2];
    const float* W_in  = (const float*)d_in[3];
    const float* b_in  = (const float*)d_in[4];
    const float* Ws    = (const float*)d_in[5];
    const float* bs    = (const float*)d_in[6];
    const float* gam   = (const float*)d_in[7];
    const float* bet   = (const float*)d_in[8];
    const float* W1    = (const float*)d_in[9];
    const float* b1    = (const float*)d_in[10];
    const float* W2    = (const float*)d_in[11];
    const float* b2    = (const float*)d_in[12];
    float* out = (float*)d_out;

    const int n = in_sizes[0] / HD;   // 100000
    const int e = in_sizes[1] / 2;    // 1600000
    const int g = out_size / EMB;     // 1024

    const int* esrc = ei;
    const int* edst = ei + e;

    // ---- workspace carve (256B aligned) ----
    char* w = (char*)d_ws;
    auto alloc = [&](size_t bytes) {
        char* p = w;
        w += (bytes + 255) & ~(size_t)255;
        return p;
    };
    float* hbuf             = (float*)alloc((size_t)n * HD * 4);
    unsigned short* hw      = (unsigned short*)alloc((size_t)n * HD * 2);  // bf16 gather table
    int*   csr_src = (int*)alloc((size_t)e * 4);
    int*   deg     = (int*)alloc((size_t)n * 4);
    float* dinv    = (float*)alloc((size_t)n * 4);
    int*   rstart  = (int*)alloc((size_t)(n + 1) * 4);
    int*   cursor  = (int*)alloc((size_t)n * 4);
    int*   bsum    = (int*)alloc(512 * 4);
    float* colsum  = (float*)alloc(256 * 4);
    float* colsumsq = colsum + HD;
    float* aff_a   = (float*)alloc(256 * 4);
    float* aff_b   = aff_a + HD;
    int*   gstart  = (int*)alloc((size_t)(g + 1) * 4);
    float* pooled  = (float*)alloc((size_t)g * HD * 4);

    hipMemsetAsync(deg, 0, (size_t)n * 4, stream);
    hipMemsetAsync(colsum, 0, 256 * 4, stream);

    const int eb = (e + 255) / 256;
    const int nb = (n + 255) / 256;

    k_hist<<<eb, 256, 0, stream>>>(edst, deg, e);
    k_dinv<<<nb, 256, 0, stream>>>(deg, dinv, n);
    k_scan_part<<<nb, 256, 0, stream>>>(deg, rstart, bsum, n);
    k_scan_mid<<<1, 512, 0, stream>>>(bsum, nb);
    k_scan_add<<<nb, 256, 0, stream>>>(rstart, bsum, n, e);
    hipMemcpyAsync(cursor, rstart, (size_t)n * 4, hipMemcpyDeviceToDevice, stream);
    k_scatter<<<eb, 256, 0, stream>>>(esrc, edst, cursor, csr_src, e);

    const int gb = (n + 63) / 64;
    // input projection: h = relu(x @ W_in + b_in)  (fp32 out)
    k_gemm<false, true, false><<<gb, 256, 0, stream>>>(x, W_in, b_in, nullptr, nullptr, hbuf, n);

    const int ab = (n + 4 * NPB - 1) / (4 * NPB);
    for (int i = 0; i < 3; ++i) {
        if (i == 0)
            k_gemm<false, false, true><<<gb, 256, 0, stream>>>(
                hbuf, Ws + (size_t)i * HD * HD, nullptr, nullptr, nullptr, hw, n);
        else
            k_gemm<true, false, true><<<gb, 256, 0, stream>>>(
                hbuf, Ws + (size_t)i * HD * HD, nullptr, aff_a, aff_b, hw, n);
        k_agg<<<ab, 256, 0, stream>>>(hw, rstart, csr_src, dinv, bs + (size_t)i * HD,
                                      hbuf, colsum, colsumsq, n);
        k_bncoef<<<1, HD, 0, stream>>>(colsum, colsumsq, gam + (size_t)i * HD,
                                       bet + (size_t)i * HD, aff_a, aff_b, n);
    }

    k_gbounds<<<(g + 256) / 256, 256, 0, stream>>>(batch, gstart, n, g);
    k_pool<<<g, 128, 0, stream>>>(hbuf, gstart, aff_a, aff_b, pooled);
    k_head<<<g, HD, 0, stream>>>(pooled, W1, b1, W2, b2, out);
}

// Round 10
// 837.682 us; speedup vs baseline: 1.5242x; 1.1291x over previous
//
#include <hip/hip_runtime.h>

#define HD 128
#define EMB 64
#define EPS 1e-5f

typedef __bf16 bf16x8 __attribute__((ext_vector_type(8)));
typedef float f32x4 __attribute__((ext_vector_type(4)));

__device__ __forceinline__ float4 ld4(const float* p) {
    return *reinterpret_cast<const float4*>(p);
}

// float -> bf16 with round-to-nearest-even
__device__ __forceinline__ unsigned short f2bf(float f) {
    unsigned u = __float_as_uint(f);
    u += 0x7FFF + ((u >> 16) & 1);
    return (unsigned short)(u >> 16);
}
__device__ __forceinline__ float bf2f(unsigned short b) {
    return __uint_as_float((unsigned)b << 16);
}
// bf16 pair unpack from packed u32 (elem0 = low 16 bits)
__device__ __forceinline__ float blo(unsigned u) { return __uint_as_float(u << 16); }
__device__ __forceinline__ float bhi(unsigned u) { return __uint_as_float(u & 0xffff0000u); }
__device__ __forceinline__ unsigned pk2(float a, float b) {
    return (unsigned)f2bf(a) | ((unsigned)f2bf(b) << 16);
}

// ---------------- degree histogram ----------------
__global__ void k_hist(const int* __restrict__ dst, int* __restrict__ deg, int e) {
    int i = blockIdx.x * blockDim.x + threadIdx.x;
    if (i < e) atomicAdd(&deg[dst[i]], 1);
}

__global__ void k_dinv(const int* __restrict__ deg, float* __restrict__ dinv, int n) {
    int i = blockIdx.x * blockDim.x + threadIdx.x;
    if (i < n) dinv[i] = 1.0f / sqrtf((float)deg[i] + 1.0f);
}

// ---------------- exclusive scan (3-phase) ----------------
__global__ void k_scan_part(const int* __restrict__ deg, int* __restrict__ out,
                            int* __restrict__ bsum, int n) {
    __shared__ int s[256];
    int i = blockIdx.x * 256 + threadIdx.x;
    int v = (i < n) ? deg[i] : 0;
    s[threadIdx.x] = v;
    __syncthreads();
    #pragma unroll
    for (int off = 1; off < 256; off <<= 1) {
        int t = (threadIdx.x >= off) ? s[threadIdx.x - off] : 0;
        __syncthreads();
        s[threadIdx.x] += t;
        __syncthreads();
    }
    if (i < n) out[i] = s[threadIdx.x] - v;         // exclusive
    if (threadIdx.x == 255) bsum[blockIdx.x] = s[255];
}

__global__ void k_scan_mid(int* __restrict__ bsum, int nb) {
    __shared__ int s[512];
    int t = threadIdx.x;
    int v = (t < nb) ? bsum[t] : 0;
    s[t] = v;
    __syncthreads();
    for (int off = 1; off < 512; off <<= 1) {
        int u = (t >= off) ? s[t - off] : 0;
        __syncthreads();
        s[t] += u;
        __syncthreads();
    }
    if (t < nb) bsum[t] = s[t] - v;                 // exclusive block offsets
}

__global__ void k_scan_add(int* __restrict__ rs, const int* __restrict__ bsum,
                           int n, int e_total) {
    int i = blockIdx.x * 256 + threadIdx.x;
    if (i < n) rs[i] += bsum[blockIdx.x];
    if (i == 0) rs[n] = e_total;
}

// ---------------- CSR scatter ----------------
__global__ void k_scatter(const int* __restrict__ src, const int* __restrict__ dst,
                          int* __restrict__ cursor, int* __restrict__ csr_src, int e) {
    int i = blockIdx.x * blockDim.x + threadIdx.x;
    if (i < e) {
        int d = dst[i];
        int pos = atomicAdd(&cursor[d], 1);
        csr_src[pos] = src[i];
    }
}

// ---------------- weight prep: Wt[m][n][k] = bf16(Wsrc[m][k][n]) ----------------
__global__ void k_wprep(const float* __restrict__ W_in, const float* __restrict__ Ws,
                        unsigned short* __restrict__ wt) {
    int m = blockIdx.x >> 7;
    int nn = blockIdx.x & 127;
    int k = threadIdx.x;
    const float* src = (m == 0) ? W_in : Ws + (size_t)(m - 1) * 16384;
    wt[(size_t)m * 16384 + nn * 128 + k] = f2bf(src[k * 128 + nn]);
}

// ---------------- bf16 MFMA GEMM: C[M,128] = act(A[M,128]) @ W[128,128] ----------------
// A fp32 (BN+relu applied at staging if APPLY_BN, then bf16-converted).
// Wt: pre-transposed bf16 weights [n][k]. Output bf16 (OUT_BF16) or fp32 (+bias+relu).
// Block: 256 thr = 4 waves; 64 rows/block; whole K=128 in one pass; 1 barrier.
// LDS XOR-swizzle (byte ^= (row&7)<<4) -> 2-way conflicts (free) on b128 frag reads.
template <bool APPLY_BN, bool OUT_BIAS_RELU, bool OUT_BF16>
__global__ __launch_bounds__(256) void k_gemm(
        const float* __restrict__ A, const unsigned short* __restrict__ Wt,
        const float* __restrict__ bias,
        const float* __restrict__ aff_a, const float* __restrict__ aff_b,
        void* __restrict__ Cout, int M) {
    __shared__ char sA[64 * 256];    // 64 rows x 128 bf16 (swizzled)
    __shared__ char sB[128 * 256];   // 128 n-rows x 128 bf16 (swizzled)
    const int tid = threadIdx.x;
    const int row0 = blockIdx.x * 64;

    // stage Wt -> sB (straight copy, swizzled)
    #pragma unroll
    for (int it = 0; it < 8; ++it) {
        int idx = it * 256 + tid;            // 16B chunk id, 0..2047
        int r = idx >> 4, c = idx & 15;
        uint4 v = reinterpret_cast<const uint4*>(Wt)[idx];
        int byte = r * 256 + c * 16;
        *reinterpret_cast<uint4*>(sB + (byte ^ ((r & 7) << 4))) = v;
    }
    // stage A -> sA: fp32 load, optional BN+relu, bf16 convert, swizzled store
    #pragma unroll
    for (int it = 0; it < 4; ++it) {
        int idx = it * 256 + tid;            // 0..1023
        int r = idx >> 4, c = idx & 15;      // row, 8-col chunk
        int gm = row0 + r;
        float4 v0 = make_float4(0.f, 0.f, 0.f, 0.f), v1 = v0;
        if (gm < M) {
            v0 = ld4(A + (size_t)gm * HD + c * 8);
            v1 = ld4(A + (size_t)gm * HD + c * 8 + 4);
        }
        if (APPLY_BN) {
            float4 a0 = ld4(aff_a + c * 8), a1 = ld4(aff_a + c * 8 + 4);
            float4 b0 = ld4(aff_b + c * 8), b1 = ld4(aff_b + c * 8 + 4);
            v0.x = fmaxf(fmaf(v0.x, a0.x, b0.x), 0.f);
            v0.y = fmaxf(fmaf(v0.y, a0.y, b0.y), 0.f);
            v0.z = fmaxf(fmaf(v0.z, a0.z, b0.z), 0.f);
            v0.w = fmaxf(fmaf(v0.w, a0.w, b0.w), 0.f);
            v1.x = fmaxf(fmaf(v1.x, a1.x, b1.x), 0.f);
            v1.y = fmaxf(fmaf(v1.y, a1.y, b1.y), 0.f);
            v1.z = fmaxf(fmaf(v1.z, a1.z, b1.z), 0.f);
            v1.w = fmaxf(fmaf(v1.w, a1.w, b1.w), 0.f);
        }
        uint4 pk;
        pk.x = pk2(v0.x, v0.y); pk.y = pk2(v0.z, v0.w);
        pk.z = pk2(v1.x, v1.y); pk.w = pk2(v1.z, v1.w);
        int byte = r * 256 + c * 16;
        *reinterpret_cast<uint4*>(sA + (byte ^ ((r & 7) << 4))) = pk;
    }
    __syncthreads();

    const int wave = tid >> 6;
    const int lane = tid & 63;
    const int l15 = lane & 15;
    const int kq  = lane >> 4;               // k-quarter within K=32 step

    // hoist A fragments: a[ks] = A[wave*16 + l15][ks*32 + kq*8 .. +8]
    bf16x8 af[4];
    {
        int arow = wave * 16 + l15;
        int base = arow * 256;
        int sw = (arow & 7) << 4;
        #pragma unroll
        for (int ks = 0; ks < 4; ++ks) {
            int byte = base + kq * 16 + ks * 64;
            af[ks] = __builtin_bit_cast(bf16x8,
                *reinterpret_cast<const uint4*>(sA + (byte ^ sw)));
        }
    }

    #pragma unroll
    for (int nt = 0; nt < 8; ++nt) {
        int bcol = nt * 16 + l15;
        int bbase = bcol * 256;
        int bsw = (bcol & 7) << 4;
        f32x4 c = {0.f, 0.f, 0.f, 0.f};
        #pragma unroll
        for (int ks = 0; ks < 4; ++ks) {
            int byte = bbase + kq * 16 + ks * 64;
            bf16x8 bf = __builtin_bit_cast(bf16x8,
                *reinterpret_cast<const uint4*>(sB + (byte ^ bsw)));
            c = __builtin_amdgcn_mfma_f32_16x16x32_bf16(af[ks], bf, c, 0, 0, 0);
        }
        // C layout: col = lane&15, row = (lane>>4)*4 + i   [m89 verified]
        int col = nt * 16 + l15;
        int grbase = row0 + wave * 16 + kq * 4;
        if (OUT_BF16) {
            unsigned short* C16 = (unsigned short*)Cout;
            #pragma unroll
            for (int i = 0; i < 4; ++i) {
                int gr = grbase + i;
                if (gr < M) C16[(size_t)gr * HD + col] = f2bf(c[i]);
            }
        } else {
            float* C32 = (float*)Cout;
            float bb = OUT_BIAS_RELU ? bias[col] : 0.f;
            #pragma unroll
            for (int i = 0; i < 4; ++i) {
                int gr = grbase + i;
                float o = c[i];
                if (OUT_BIAS_RELU) o = fmaxf(o + bb, 0.f);
                if (gr < M) C32[(size_t)gr * HD + col] = o;
            }
        }
    }
}

// ---------------- per-node aggregation + BN stats (4 edges per gather instr) ----------
#define NPB 8
__global__ void k_agg(const unsigned short* __restrict__ hw, const int* __restrict__ row_start,
                      const int* __restrict__ csr_src, const float* __restrict__ dinv,
                      const float* __restrict__ bias_row, float* __restrict__ h_pre,
                      float* __restrict__ colsum, float* __restrict__ colsumsq, int n) {
    const int tid  = threadIdx.x;
    const int lane = tid & 63;
    const int slot = tid >> 6;       // wave id 0..3
    const int q    = lane & 15;      // 16B slice (features q*8 .. q*8+7)
    const int grp  = lane >> 4;      // edge group 0..3
    const int n0 = blockIdx.x * (4 * NPB);
    const uint4* __restrict__ hw4 = (const uint4*)hw;   // row = 16 x uint4

    float b8[8];
    #pragma unroll
    for (int k = 0; k < 8; ++k) b8[k] = bias_row[q * 8 + k];

    float psum8[8], psq8[8];
    #pragma unroll
    for (int k = 0; k < 8; ++k) { psum8[k] = 0.f; psq8[k] = 0.f; }

    for (int nn = 0; nn < NPB; ++nn) {
        int node = n0 + nn * 4 + slot;     // wave-uniform
        if (node >= n) continue;
        float dn = dinv[node];
        float acc[8];
        #pragma unroll
        for (int k = 0; k < 8; ++k) acc[k] = 0.f;

        const int jb = row_start[node], je = row_start[node + 1];
        for (int j = jb; j < je; j += 8) {
            int e0 = j + grp;
            int s0 = (e0 < je) ? csr_src[e0] : 0;
            float w0 = (e0 < je) ? dinv[s0] * dn : 0.f;
            uint4 r0 = hw4[(size_t)s0 * 16 + q];
            int e1 = j + 4 + grp;
            int s1 = (e1 < je) ? csr_src[e1] : 0;
            float w1 = (e1 < je) ? dinv[s1] * dn : 0.f;
            uint4 r1 = hw4[(size_t)s1 * 16 + q];

            acc[0] = fmaf(blo(r0.x), w0, acc[0]); acc[1] = fmaf(bhi(r0.x), w0, acc[1]);
            acc[2] = fmaf(blo(r0.y), w0, acc[2]); acc[3] = fmaf(bhi(r0.y), w0, acc[3]);
            acc[4] = fmaf(blo(r0.z), w0, acc[4]); acc[5] = fmaf(bhi(r0.z), w0, acc[5]);
            acc[6] = fmaf(blo(r0.w), w0, acc[6]); acc[7] = fmaf(bhi(r0.w), w0, acc[7]);

            acc[0] = fmaf(blo(r1.x), w1, acc[0]); acc[1] = fmaf(bhi(r1.x), w1, acc[1]);
            acc[2] = fmaf(blo(r1.y), w1, acc[2]); acc[3] = fmaf(bhi(r1.y), w1, acc[3]);
            acc[4] = fmaf(blo(r1.z), w1, acc[4]); acc[5] = fmaf(bhi(r1.z), w1, acc[5]);
            acc[6] = fmaf(blo(r1.w), w1, acc[6]); acc[7] = fmaf(bhi(r1.w), w1, acc[7]);
        }

        #pragma unroll
        for (int k = 0; k < 8; ++k) acc[k] += __shfl_xor(acc[k], 16, 64);
        #pragma unroll
        for (int k = 0; k < 8; ++k) acc[k] += __shfl_xor(acc[k], 32, 64);

        uint4 ow = hw4[(size_t)node * 16 + q];
        float sn = dn * dn;
        acc[0] = fmaf(blo(ow.x), sn, acc[0] + b8[0]);
        acc[1] = fmaf(bhi(ow.x), sn, acc[1] + b8[1]);
        acc[2] = fmaf(blo(ow.y), sn, acc[2] + b8[2]);
        acc[3] = fmaf(bhi(ow.y), sn, acc[3] + b8[3]);
        acc[4] = fmaf(blo(ow.z), sn, acc[4] + b8[4]);
        acc[5] = fmaf(bhi(ow.z), sn, acc[5] + b8[5]);
        acc[6] = fmaf(blo(ow.w), sn, acc[6] + b8[6]);
        acc[7] = fmaf(bhi(ow.w), sn, acc[7] + b8[7]);

        if (grp == 0) {
            float* dst = h_pre + (size_t)node * HD + q * 8;
            *reinterpret_cast<float4*>(dst)     = make_float4(acc[0], acc[1], acc[2], acc[3]);
            *reinterpret_cast<float4*>(dst + 4) = make_float4(acc[4], acc[5], acc[6], acc[7]);
            #pragma unroll
            for (int k = 0; k < 8; ++k) {
                psum8[k] += acc[k];
                psq8[k] = fmaf(acc[k], acc[k], psq8[k]);
            }
        }
    }

    __shared__ float redS[4][128];
    __shared__ float redQ[4][128];
    if (grp == 0) {
        #pragma unroll
        for (int k = 0; k < 8; ++k) {
            redS[slot][q * 8 + k] = psum8[k];
            redQ[slot][q * 8 + k] = psq8[k];
        }
    }
    __syncthreads();
    int f = tid & 127;
    if (tid < 128) {
        float s = redS[0][f] + redS[1][f] + redS[2][f] + redS[3][f];
        atomicAdd(&colsum[f], s);
    } else {
        float s = redQ[0][f] + redQ[1][f] + redQ[2][f] + redQ[3][f];
        atomicAdd(&colsumsq[f], s);
    }
}

// ---------------- BN coefficients (+ reset accumulators for next layer) ----------------
__global__ void k_bncoef(float* __restrict__ colsum, float* __restrict__ colsumsq,
                         const float* __restrict__ gamma, const float* __restrict__ beta,
                         float* __restrict__ aff_a, float* __restrict__ aff_b, int n) {
    int f = threadIdx.x;
    float inv_n = 1.0f / (float)n;
    float mean = colsum[f] * inv_n;
    float var = colsumsq[f] * inv_n - mean * mean;
    float rstd = 1.0f / sqrtf(var + EPS);
    float a = gamma[f] * rstd;
    aff_a[f] = a;
    aff_b[f] = beta[f] - mean * a;
    colsum[f] = 0.f;
    colsumsq[f] = 0.f;
}

// ---------------- graph boundaries (batch sorted) ----------------
__global__ void k_gbounds(const int* __restrict__ batch, int* __restrict__ gstart,
                          int n, int g) {
    int gi = blockIdx.x * blockDim.x + threadIdx.x;
    if (gi > g) return;
    int lo = 0, hi = n;
    while (lo < hi) {
        int mid = (lo + hi) >> 1;
        if (batch[mid] < gi) lo = mid + 1; else hi = mid;
    }
    gstart[gi] = lo;
}

// ---------------- per-graph mean pool with fused BN+relu (float2, 2 half-waves) --------
__global__ void k_pool(const float* __restrict__ h_pre, const int* __restrict__ gstart,
                       const float* __restrict__ aff_a, const float* __restrict__ aff_b,
                       float* __restrict__ pooled) {
    const int gi = blockIdx.x;
    const int tid = threadIdx.x;
    const int lane = tid & 63;
    const int half = tid >> 6;          // 0/1: alternate rows
    const float2* __restrict__ h2 = (const float2*)h_pre;
    const float2 a2 = *((const float2*)aff_a + lane);
    const float2 b2 = *((const float2*)aff_b + lane);
    int s = gstart[gi], e = gstart[gi + 1];
    float2 sum = make_float2(0.f, 0.f);
    for (int i = s + half; i < e; i += 2) {
        float2 v = h2[(size_t)i * 64 + lane];
        sum.x += fmaxf(fmaf(v.x, a2.x, b2.x), 0.f);
        sum.y += fmaxf(fmaf(v.y, a2.y, b2.y), 0.f);
    }
    __shared__ float2 red[128];
    red[tid] = sum;
    __syncthreads();
    if (half == 0) {
        float2 o = red[tid + 64];
        sum.x += o.x; sum.y += o.y;
        float inv = 1.0f / fmaxf((float)(e - s), 1.0f);
        float2* p2 = (float2*)pooled;
        p2[(size_t)gi * 64 + lane] = make_float2(sum.x * inv, sum.y * inv);
    }
}

// ---------------- head MLP: out = relu(p@W1+b1)@W2+b2 ----------------
__global__ void k_head(const float* __restrict__ pooled, const float* __restrict__ W1,
                       const float* __restrict__ b1, const float* __restrict__ W2,
                       const float* __restrict__ b2, float* __restrict__ out) {
    __shared__ float p[HD];
    __shared__ float t[HD];
    int gi = blockIdx.x;
    int j = threadIdx.x;
    p[j] = pooled[(size_t)gi * HD + j];
    __syncthreads();
    float acc = b1[j];
    #pragma unroll 8
    for (int k = 0; k < HD; ++k) acc = fmaf(p[k], W1[(size_t)k * HD + j], acc);
    t[j] = fmaxf(acc, 0.f);
    __syncthreads();
    if (j < EMB) {
        float o = b2[j];
        #pragma unroll 8
        for (int k = 0; k < HD; ++k) o = fmaf(t[k], W2[(size_t)k * EMB + j], o);
        out[(size_t)gi * EMB + j] = o;
    }
}

extern "C" void kernel_launch(void* const* d_in, const int* in_sizes, int n_in,
                              void* d_out, int out_size, void* d_ws, size_t ws_size,
                              hipStream_t stream) {
    const float* x     = (const float*)d_in[0];
    const int*   ei    = (const int*)d_in[1];
    const int*   batch = (const int*)d_in[2];
    const float* W_in  = (const float*)d_in[3];
    const float* b_in  = (const float*)d_in[4];
    const float* Ws    = (const float*)d_in[5];
    const float* bs    = (const float*)d_in[6];
    const float* gam   = (const float*)d_in[7];
    const float* bet   = (const float*)d_in[8];
    const float* W1    = (const float*)d_in[9];
    const float* b1    = (const float*)d_in[10];
    const float* W2    = (const float*)d_in[11];
    const float* b2    = (const float*)d_in[12];
    float* out = (float*)d_out;

    const int n = in_sizes[0] / HD;   // 100000
    const int e = in_sizes[1] / 2;    // 1600000
    const int g = out_size / EMB;     // 1024

    const int* esrc = ei;
    const int* edst = ei + e;

    // ---- workspace carve (256B aligned) ----
    char* w = (char*)d_ws;
    auto alloc = [&](size_t bytes) {
        char* p = w;
        w += (bytes + 255) & ~(size_t)255;
        return p;
    };
    float* hbuf             = (float*)alloc((size_t)n * HD * 4);
    unsigned short* hw      = (unsigned short*)alloc((size_t)n * HD * 2);  // bf16 gather table
    unsigned short* wtbuf   = (unsigned short*)alloc((size_t)4 * HD * HD * 2); // bf16 W^T x4
    int*   csr_src = (int*)alloc((size_t)e * 4);
    int*   deg     = (int*)alloc((size_t)n * 4);
    float* dinv    = (float*)alloc((size_t)n * 4);
    int*   rstart  = (int*)alloc((size_t)(n + 1) * 4);
    int*   cursor  = (int*)alloc((size_t)n * 4);
    int*   bsum    = (int*)alloc(512 * 4);
    float* colsum  = (float*)alloc(256 * 4);
    float* colsumsq = colsum + HD;
    float* aff_a   = (float*)alloc(256 * 4);
    float* aff_b   = aff_a + HD;
    int*   gstart  = (int*)alloc((size_t)(g + 1) * 4);
    float* pooled  = (float*)alloc((size_t)g * HD * 4);

    hipMemsetAsync(deg, 0, (size_t)n * 4, stream);
    hipMemsetAsync(colsum, 0, 256 * 4, stream);

    const int eb = (e + 255) / 256;
    const int nb = (n + 255) / 256;

    k_wprep<<<512, 128, 0, stream>>>(W_in, Ws, wtbuf);
    k_hist<<<eb, 256, 0, stream>>>(edst, deg, e);
    k_dinv<<<nb, 256, 0, stream>>>(deg, dinv, n);
    k_scan_part<<<nb, 256, 0, stream>>>(deg, rstart, bsum, n);
    k_scan_mid<<<1, 512, 0, stream>>>(bsum, nb);
    k_scan_add<<<nb, 256, 0, stream>>>(rstart, bsum, n, e);
    hipMemcpyAsync(cursor, rstart, (size_t)n * 4, hipMemcpyDeviceToDevice, stream);
    k_scatter<<<eb, 256, 0, stream>>>(esrc, edst, cursor, csr_src, e);

    const int gb = (n + 63) / 64;
    // input projection: h = relu(x @ W_in + b_in)  (fp32 out)
    k_gemm<false, true, false><<<gb, 256, 0, stream>>>(
        x, wtbuf, b_in, nullptr, nullptr, hbuf, n);

    const int ab = (n + 4 * NPB - 1) / (4 * NPB);
    for (int i = 0; i < 3; ++i) {
        if (i == 0)
            k_gemm<false, false, true><<<gb, 256, 0, stream>>>(
                hbuf, wtbuf + (size_t)(i + 1) * HD * HD, nullptr, nullptr, nullptr, hw, n);
        else
            k_gemm<true, false, true><<<gb, 256, 0, stream>>>(
                hbuf, wtbuf + (size_t)(i + 1) * HD * HD, nullptr, aff_a, aff_b, hw, n);
        k_agg<<<ab, 256, 0, stream>>>(hw, rstart, csr_src, dinv, bs + (size_t)i * HD,
                                      hbuf, colsum, colsumsq, n);
        k_bncoef<<<1, HD, 0, stream>>>(colsum, colsumsq, gam + (size_t)i * HD,
                                       bet + (size_t)i * HD, aff_a, aff_b, n);
    }

    k_gbounds<<<(g + 256) / 256, 256, 0, stream>>>(batch, gstart, n, g);
    k_pool<<<g, 128, 0, stream>>>(hbuf, gstart, aff_a, aff_b, pooled);
    k_head<<<g, HD, 0, stream>>>(pooled, W1, b1, W2, b2, out);
}